// Round 5
// baseline (1131.435 us; speedup 1.0000x reference)
//
#include <hip/hip_runtime.h>
#include <hip/hip_fp16.h>

#define N_NODES 50000
#define N_EDGES 800000
#define IN_DIM  128
#define EDGE_DIM 16
#define HID     64
#define HID2    128
#define OUT_DIM 8
#define N_LAYERS 4

typedef _Float16 half8 __attribute__((ext_vector_type(8)));
typedef float floatx4 __attribute__((ext_vector_type(4)));

// ---------------------------------------------------------------------------
// Counting sort of edges by dst: histogram -> exclusive scan -> scatter.
// ---------------------------------------------------------------------------
__global__ __launch_bounds__(256, 4) void hist_kernel(
    const int* __restrict__ dsts, int* __restrict__ deg)
{
    for (int e = blockIdx.x * 256 + threadIdx.x; e < N_EDGES;
         e += gridDim.x * 256)
        atomicAdd(&deg[dsts[e]], 1);
}

// single block, 1024 threads; exclusive scan; writes offsets AND cursor copy
__global__ __launch_bounds__(1024, 1) void scan_kernel(
    const int* __restrict__ deg, int* __restrict__ offsets,
    int* __restrict__ cursor)
{
    __shared__ int part[1024];
    const int t = threadIdx.x;
    const int CHUNK = (N_NODES + 1023) / 1024;           // 49
    const int lo = t * CHUNK;
    const int hi = min(lo + CHUNK, N_NODES);
    int sum = 0;
    for (int i = lo; i < hi; ++i) sum += deg[i];
    part[t] = sum;
    __syncthreads();
    for (int off = 1; off < 1024; off <<= 1) {           // Hillis-Steele incl.
        int v_ = (t >= off) ? part[t - off] : 0;
        __syncthreads();
        part[t] += v_;
        __syncthreads();
    }
    int run = (t > 0) ? part[t - 1] : 0;                 // exclusive base
    for (int i = lo; i < hi; ++i) {
        offsets[i] = run; cursor[i] = run; run += deg[i];
    }
    if (t == 1023) offsets[N_NODES] = part[1023];        // total
}

// pos = cursor[dst]++ ; inv[e]=pos ; ssrc[pos]=src[e] ; sdst[pos]=dst
__global__ __launch_bounds__(256, 4) void scatter_kernel(
    const int* __restrict__ srcs, const int* __restrict__ dsts,
    int* __restrict__ cursor, int* __restrict__ inv,
    int* __restrict__ ssrc, int* __restrict__ sdst)
{
    for (int e = blockIdx.x * 256 + threadIdx.x; e < N_EDGES;
         e += gridDim.x * 256) {
        const int d = dsts[e];
        const int pos = atomicAdd(&cursor[d], 1);
        inv[e] = pos;
        ssrc[pos] = srcs[e];
        sdst[pos] = d;
    }
}

// ---------------------------------------------------------------------------
// h0 = x @ node_W + node_b      [N,128]@[128,64]; also fp16 copy for gathers
// ---------------------------------------------------------------------------
__global__ __launch_bounds__(256, 2) void node_proj_kernel(
    const float* __restrict__ x, const float* __restrict__ W,
    const float* __restrict__ b, float* __restrict__ h, __half* __restrict__ zh)
{
    __shared__ float xs[4][IN_DIM];
    const int c = threadIdx.x & 63;
    const int local_n = threadIdx.x >> 6;
    float w[IN_DIM];
#pragma unroll
    for (int k = 0; k < IN_DIM; ++k) w[k] = W[k * HID + c];
    const float bias = b[c];

    for (int base = blockIdx.x * 4; base < N_NODES; base += gridDim.x * 4) {
        __syncthreads();
#pragma unroll
        for (int i = 0; i < 2; ++i) {
            int idx = threadIdx.x + i * 256;
            int nn = idx >> 7, kk = idx & 127;
            xs[nn][kk] = x[(base + nn) * IN_DIM + kk];
        }
        __syncthreads();
        const int n = base + local_n;
        float acc = bias;
#pragma unroll
        for (int k4 = 0; k4 < IN_DIM / 4; ++k4) {
            float4 xv = ((const float4*)xs[local_n])[k4];
            acc = fmaf(xv.x, w[k4 * 4 + 0], acc);
            acc = fmaf(xv.y, w[k4 * 4 + 1], acc);
            acc = fmaf(xv.z, w[k4 * 4 + 2], acc);
            acc = fmaf(xv.w, w[k4 * 4 + 3], acc);
        }
        h[n * HID + c] = acc;
        zh[n * HID + c] = __float2half(acc);
    }
}

// ---------------------------------------------------------------------------
// edge embedding via MFMA. One wave handles 16 edges:
//   A[16x32] = edge attrs (K=16 real, padded w/ zeros to 32), fp16
//   B[32x64] = edge_W (4 blocks of 16 cols), fp16   -> 4x mfma 16x16x32
// C layout: col=lane&15, row=(lane>>4)*4+reg (verified). LDS transpose ->
// contiguous 128B store per edge at eah[inv[e]].
// ---------------------------------------------------------------------------
__global__ __launch_bounds__(256, 4) void edge_emb_kernel(
    const float* __restrict__ ea, const float* __restrict__ W,
    const float* __restrict__ b, const int* __restrict__ inv,
    __half* __restrict__ eah)
{
    __shared__ __half lds_t[4][16 * HID];            // 2KB per wave
    const int lane = threadIdx.x & 63;
    const int waveid = threadIdx.x >> 6;
    const int wave = (blockIdx.x * 256 + threadIdx.x) >> 6;
    const int nwaves = gridDim.x * 4;
    const int m = lane & 15, q = lane >> 4;
    const int NT = N_EDGES / 16;                     // 50000

    // B fragments: bf[blk][i] = W[k= q*8+i][blk*16 + m], zero for k>=16
    half8 bf[4];
#pragma unroll
    for (int blk = 0; blk < 4; ++blk) {
#pragma unroll
        for (int i = 0; i < 8; ++i) {
            const int k = q * 8 + i;
            bf[blk][i] = (k < EDGE_DIM)
                ? (_Float16)W[k * HID + blk * 16 + m] : (_Float16)0.f;
        }
    }
    float bv[4];
#pragma unroll
    for (int blk = 0; blk < 4; ++blk) bv[blk] = b[blk * 16 + m];

    const int ed = lane >> 3, ch = lane & 7;         // store mapping

    for (int tile = wave; tile < NT; tile += nwaves) {
        const int e0 = tile * 16;
        // A fragment: af[i] = ea[e0+m][k=q*8+i] (zero for k>=16)
        half8 af;
#pragma unroll
        for (int i = 0; i < 8; ++i) af[i] = (_Float16)0.f;
        if (q < 2) {
            const float4* ap =
                (const float4*)(ea + (size_t)(e0 + m) * EDGE_DIM + q * 8);
            const float4 lo = ap[0];
            const float4 hi = ap[1];
            af[0] = (_Float16)lo.x; af[1] = (_Float16)lo.y;
            af[2] = (_Float16)lo.z; af[3] = (_Float16)lo.w;
            af[4] = (_Float16)hi.x; af[5] = (_Float16)hi.y;
            af[6] = (_Float16)hi.z; af[7] = (_Float16)hi.w;
        }
        floatx4 c[4];
#pragma unroll
        for (int blk = 0; blk < 4; ++blk) {
            floatx4 cin = {bv[blk], bv[blk], bv[blk], bv[blk]};
            c[blk] = __builtin_amdgcn_mfma_f32_16x16x32_f16(
                af, bf[blk], cin, 0, 0, 0);
        }
        // transpose via per-wave LDS: lds[row=edge][col=channel]
#pragma unroll
        for (int blk = 0; blk < 4; ++blk)
#pragma unroll
            for (int r = 0; r < 4; ++r)
                lds_t[waveid][(q * 4 + r) * HID + blk * 16 + m] =
                    __float2half(c[blk][r]);
        // read back 2x 16B per lane, scatter-store 128B per edge
        const int pos0 = inv[e0 + ed];
        const int pos1 = inv[e0 + 8 + ed];
        const float4 v0 =
            *(const float4*)&lds_t[waveid][ed * HID + ch * 8];
        const float4 v1 =
            *(const float4*)&lds_t[waveid][(8 + ed) * HID + ch * 8];
        ((float4*)(eah + (size_t)pos0 * HID))[ch] = v0;
        ((float4*)(eah + (size_t)pos1 * HID))[ch] = v1;
    }
}

// ---------------------------------------------------------------------------
// Edge-major segmented softmax-aggregate. Wave owns 64 sorted edges;
// S/P accumulated per dst-segment, flushed via atomics at boundaries only.
// p,s must be zeroed before launch. agg finalize (p/(s+eps)) is in the MLP.
// ---------------------------------------------------------------------------
__global__ __launch_bounds__(256, 4) void edge_agg_kernel(
    const __half* __restrict__ zh, const __half* __restrict__ eah,
    const int* __restrict__ ssrc, const int* __restrict__ sdst,
    const float* __restrict__ conv_t, int layer,
    float* __restrict__ p, float* __restrict__ s)
{
    const int lane = threadIdx.x & 63;
    const int wave = (blockIdx.x * 256 + threadIdx.x) >> 6;
    const int nwaves = gridDim.x * 4;
    const float t = conv_t[layer];
    const int NT = N_EDGES / 64;                     // 12500

    for (int tile = wave; tile < NT; tile += nwaves) {
        const int e0 = tile * 64;
        const int sv = ssrc[e0 + lane];              // 64 srcs, lane-resident
        const int dv = sdst[e0 + lane];              // 64 dsts
        float S = 0.f, P = 0.f;
        int cur = __builtin_amdgcn_readlane(dv, 0);
#pragma unroll 1
        for (int j = 0; j < 64; j += 8) {
            float z[8], e[8];
#pragma unroll
            for (int k = 0; k < 8; ++k) {
                const int a = __builtin_amdgcn_readlane(sv, j + k);
                z[k] = __half2float(zh[(size_t)a * HID + lane]);
            }
#pragma unroll
            for (int k = 0; k < 8; ++k)
                e[k] = __half2float(eah[(size_t)(e0 + j + k) * HID + lane]);
#pragma unroll
            for (int k = 0; k < 8; ++k) {
                const int d = __builtin_amdgcn_readlane(dv, j + k);
                if (d != cur) {                      // wave-uniform branch
                    unsafeAtomicAdd(&s[(size_t)cur * HID + lane], S);
                    unsafeAtomicAdd(&p[(size_t)cur * HID + lane], P);
                    S = 0.f; P = 0.f; cur = d;
                }
                const float m = fmaxf(z[k] + e[k], 0.f) + 1e-7f;
                const float xx = __expf(m * t);
                S += xx;
                P = fmaf(m, xx, P);
            }
        }
        unsafeAtomicAdd(&s[(size_t)cur * HID + lane], S);
        unsafeAtomicAdd(&p[(size_t)cur * HID + lane], P);
    }
}

// ---------------------------------------------------------------------------
// Fused node MLP: hin = p/(s+eps) + zin ; u = hin@W1+b1 ;
// v = relu(LN128(u)*g1+be1) (in LDS) ; out2 = v@W2+b2 ;
// h = (residual? h:0)+out2 ; z = relu(LN64(h)*gz+bz) ; zh = fp16(z)
// block = 256 thr = 2 nodes. mm1: thr=(nn,j∈128). mm2: wave=(nn,khalf),
// 64-wide k-split combined through LDS.
// ---------------------------------------------------------------------------
__global__ __launch_bounds__(256, 2) void node_mlp_kernel(
    const float* __restrict__ p, const float* __restrict__ s,
    const float* __restrict__ zin,
    const float* __restrict__ W1, const float* __restrict__ b1,
    const float* __restrict__ g1, const float* __restrict__ be1,
    const float* __restrict__ W2, const float* __restrict__ b2,
    const float* __restrict__ lng, const float* __restrict__ lnb,
    float* __restrict__ h, float* __restrict__ z, __half* __restrict__ zh,
    int residual)
{
    __shared__ float hs[2][HID];
    __shared__ float vs[2][HID2];
    __shared__ float red[2][2][2];
    __shared__ float red2[2][HID];
    const int j = threadIdx.x & 127;
    const int nn1 = threadIdx.x >> 7;
    const int wavehalf = (threadIdx.x >> 6) & 1;
    const int waveid = threadIdx.x >> 6;
    const int nn2 = waveid >> 1;
    const int khalf = waveid & 1;
    const int lane = threadIdx.x & 63;

    float w1[HID];
#pragma unroll
    for (int k = 0; k < HID; ++k) w1[k] = W1[k * HID2 + j];
    float w2[HID];
#pragma unroll
    for (int k = 0; k < HID; ++k) w2[k] = W2[(khalf * HID + k) * HID + lane];
    const float bias1 = b1[j], g1v = g1[j], be1v = be1[j];
    const float bias2 = b2[lane], gz = lng[lane], bz = lnb[lane];

    for (int base = blockIdx.x * 2; base < N_NODES; base += gridDim.x * 2) {
        __syncthreads();
        if (threadIdx.x < 128) {
            const int nn = threadIdx.x >> 6, c = threadIdx.x & 63;
            const int idx = (base + nn) * HID + c;
            hs[nn][c] = p[idx] / (s[idx] + 1e-16f) + zin[idx];
        }
        __syncthreads();
        // ---- mm1 + LN128 + relu -> vs ----
        float u = bias1;
#pragma unroll
        for (int k4 = 0; k4 < HID / 4; ++k4) {
            float4 hv = ((const float4*)hs[nn1])[k4];
            u = fmaf(hv.x, w1[k4 * 4 + 0], u);
            u = fmaf(hv.y, w1[k4 * 4 + 1], u);
            u = fmaf(hv.z, w1[k4 * 4 + 2], u);
            u = fmaf(hv.w, w1[k4 * 4 + 3], u);
        }
        float ps_ = u;
#pragma unroll
        for (int o = 1; o < 64; o <<= 1) ps_ += __shfl_xor(ps_, o, 64);
        if (lane == 0) red[nn1][0][wavehalf] = ps_;
        __syncthreads();
        const float mu = (red[nn1][0][0] + red[nn1][0][1]) * (1.f / 128.f);
        const float d = u - mu;
        float q = d * d;
#pragma unroll
        for (int o = 1; o < 64; o <<= 1) q += __shfl_xor(q, o, 64);
        if (lane == 0) red[nn1][1][wavehalf] = q;
        __syncthreads();
        const float var = (red[nn1][1][0] + red[nn1][1][1]) * (1.f / 128.f);
        const float y = d * rsqrtf(var + 1e-5f) * g1v + be1v;
        vs[nn1][j] = y > 0.f ? y : 0.f;
        __syncthreads();
        // ---- mm2 (k-split by wave) ----
        float acc = 0.f;
        const float* vrow = vs[nn2] + khalf * HID;
#pragma unroll
        for (int k4 = 0; k4 < HID / 4; ++k4) {
            float4 vv = ((const float4*)vrow)[k4];
            acc = fmaf(vv.x, w2[k4 * 4 + 0], acc);
            acc = fmaf(vv.y, w2[k4 * 4 + 1], acc);
            acc = fmaf(vv.z, w2[k4 * 4 + 2], acc);
            acc = fmaf(vv.w, w2[k4 * 4 + 3], acc);
        }
        if (khalf == 1) red2[nn2][lane] = acc;
        __syncthreads();
        if (khalf == 0) {
            const int n = base + nn2;
            const float tot = acc + red2[nn2][lane] + bias2;
            const float hn = residual ? (h[n * HID + lane] + tot) : tot;
            h[n * HID + lane] = hn;
            float ps2 = hn;
#pragma unroll
            for (int o = 1; o < 64; o <<= 1) ps2 += __shfl_xor(ps2, o, 64);
            const float mu2 = ps2 * (1.f / 64.f);
            const float d2 = hn - mu2;
            float q2 = d2 * d2;
#pragma unroll
            for (int o = 1; o < 64; o <<= 1) q2 += __shfl_xor(q2, o, 64);
            const float var2 = q2 * (1.f / 64.f);
            const float y2 = d2 * rsqrtf(var2 + 1e-5f) * gz + bz;
            const float zr = y2 > 0.f ? y2 : 0.f;
            z[n * HID + lane] = zr;
            zh[n * HID + lane] = __float2half(zr);
        }
    }
}

// ---------------------------------------------------------------------------
// out = z @ lin_W + lin_b      [N,64]@[64,8]
// ---------------------------------------------------------------------------
__global__ __launch_bounds__(256, 4) void final_kernel(
    const float* __restrict__ z, const float* __restrict__ Wl,
    const float* __restrict__ bl, float* __restrict__ out)
{
    __shared__ float wl[HID * OUT_DIM];
    for (int i = threadIdx.x; i < HID * OUT_DIM; i += 256) wl[i] = Wl[i];
    __syncthreads();
    const int total = N_NODES * OUT_DIM;
    for (int idx = blockIdx.x * 256 + threadIdx.x; idx < total;
         idx += gridDim.x * 256) {
        const int n = idx >> 3, o = idx & 7;
        const float4* zp4 = (const float4*)(z + n * HID);
        float acc = bl[o];
#pragma unroll
        for (int k4 = 0; k4 < HID / 4; ++k4) {
            float4 zv = zp4[k4];
            acc = fmaf(zv.x, wl[(k4 * 4 + 0) * OUT_DIM + o], acc);
            acc = fmaf(zv.y, wl[(k4 * 4 + 1) * OUT_DIM + o], acc);
            acc = fmaf(zv.z, wl[(k4 * 4 + 2) * OUT_DIM + o], acc);
            acc = fmaf(zv.w, wl[(k4 * 4 + 3) * OUT_DIM + o], acc);
        }
        out[idx] = acc;
    }
}

// ---------------------------------------------------------------------------
extern "C" void kernel_launch(void* const* d_in, const int* in_sizes, int n_in,
                              void* d_out, int out_size, void* d_ws, size_t ws_size,
                              hipStream_t stream)
{
    const float* x         = (const float*)d_in[0];
    const float* edge_attr = (const float*)d_in[1];
    const float* node_W    = (const float*)d_in[2];
    const float* node_b    = (const float*)d_in[3];
    const float* edge_W    = (const float*)d_in[4];
    const float* edge_b    = (const float*)d_in[5];
    const float* conv_t    = (const float*)d_in[6];
    const float* conv_W1   = (const float*)d_in[7];
    const float* conv_b1   = (const float*)d_in[8];
    const float* conv_g1   = (const float*)d_in[9];
    const float* conv_be1  = (const float*)d_in[10];
    const float* conv_W2   = (const float*)d_in[11];
    const float* conv_b2   = (const float*)d_in[12];
    const float* ln_g      = (const float*)d_in[13];
    const float* ln_b      = (const float*)d_in[14];
    const float* lin_W     = (const float*)d_in[15];
    const float* lin_b     = (const float*)d_in[16];
    const int*   edge_index= (const int*)d_in[17];
    const int*   srcs = edge_index;
    const int*   dsts = edge_index + N_EDGES;
    float* out = (float*)d_out;

    // workspace layout (~173 MB)
    float* h   = (float*)d_ws;                    // N*64
    float* z   = h   + N_NODES * HID;             // N*64
    float* p   = z   + N_NODES * HID;             // N*64
    float* s   = p   + N_NODES * HID;             // N*64 (contiguous w/ p)
    __half* zh  = (__half*)(s + N_NODES * HID);   // N*64 half
    __half* eah = zh + (size_t)N_NODES * HID;     // E*64 half
    int* deg     = (int*)(eah + (size_t)N_EDGES * HID); // N
    int* offsets = deg + N_NODES;                 // N+1
    int* cursor  = offsets + N_NODES + 1;         // N
    int* inv     = cursor + N_NODES;              // E
    int* ssrc    = inv + N_EDGES;                 // E
    int* sdst    = ssrc + N_EDGES;                // E

    // ---- counting sort of edges by dst (once per call) ----
    hipMemsetAsync(deg, 0, (size_t)N_NODES * sizeof(int), stream);
    hist_kernel<<<1024, 256, 0, stream>>>(dsts, deg);
    scan_kernel<<<1, 1024, 0, stream>>>(deg, offsets, cursor);
    scatter_kernel<<<1024, 256, 0, stream>>>(srcs, dsts, cursor, inv, ssrc, sdst);

    node_proj_kernel<<<2048, 256, 0, stream>>>(x, node_W, node_b, h, zh);
    edge_emb_kernel<<<3125, 256, 0, stream>>>(edge_attr, edge_W, edge_b, inv, eah);

    for (int layer = 0; layer < N_LAYERS; ++layer) {
        const float* zin = (layer == 0) ? h : z;
        hipMemsetAsync(p, 0, (size_t)2 * N_NODES * HID * sizeof(float), stream);
        edge_agg_kernel<<<3125, 256, 0, stream>>>(zh, eah, ssrc, sdst,
                                                  conv_t, layer, p, s);
        const float* gz = (layer < N_LAYERS - 1) ? (ln_g + (layer + 1) * HID) : ln_g;
        const float* bz = (layer < N_LAYERS - 1) ? (ln_b + (layer + 1) * HID) : ln_b;
        node_mlp_kernel<<<3125, 256, 0, stream>>>(
            p, s, zin,
            conv_W1 + (size_t)layer * HID * HID2, conv_b1 + layer * HID2,
            conv_g1 + layer * HID2, conv_be1 + layer * HID2,
            conv_W2 + (size_t)layer * HID2 * HID, conv_b2 + layer * HID,
            gz, bz, h, z, zh, layer > 0 ? 1 : 0);
    }
    final_kernel<<<1024, 256, 0, stream>>>(z, lin_W, lin_b, out);
}

// Round 6
// 916.456 us; speedup vs baseline: 1.2346x; 1.2346x over previous
//
#include <hip/hip_runtime.h>
#include <hip/hip_fp16.h>

#define N_NODES 50000
#define N_EDGES 800000
#define IN_DIM  128
#define EDGE_DIM 16
#define HID     64
#define HID2    128
#define OUT_DIM 8
#define N_LAYERS 4

typedef _Float16 half8 __attribute__((ext_vector_type(8)));
typedef float floatx4 __attribute__((ext_vector_type(4)));

// ---------------------------------------------------------------------------
// Counting sort of edges by dst: histogram -> exclusive scan -> scatter.
// ---------------------------------------------------------------------------
__global__ __launch_bounds__(256, 4) void hist_kernel(
    const int* __restrict__ dsts, int* __restrict__ deg)
{
    for (int e = blockIdx.x * 256 + threadIdx.x; e < N_EDGES;
         e += gridDim.x * 256)
        atomicAdd(&deg[dsts[e]], 1);
}

// single block, 1024 threads; exclusive scan; writes offsets AND cursor copy
__global__ __launch_bounds__(1024, 1) void scan_kernel(
    const int* __restrict__ deg, int* __restrict__ offsets,
    int* __restrict__ cursor)
{
    __shared__ int part[1024];
    const int t = threadIdx.x;
    const int CHUNK = (N_NODES + 1023) / 1024;           // 49
    const int lo = t * CHUNK;
    const int hi = min(lo + CHUNK, N_NODES);
    int sum = 0;
    for (int i = lo; i < hi; ++i) sum += deg[i];
    part[t] = sum;
    __syncthreads();
    for (int off = 1; off < 1024; off <<= 1) {           // Hillis-Steele incl.
        int v_ = (t >= off) ? part[t - off] : 0;
        __syncthreads();
        part[t] += v_;
        __syncthreads();
    }
    int run = (t > 0) ? part[t - 1] : 0;                 // exclusive base
    for (int i = lo; i < hi; ++i) {
        offsets[i] = run; cursor[i] = run; run += deg[i];
    }
    if (t == 1023) offsets[N_NODES] = part[1023];        // total
}

// pos = cursor[dst]++ ; inv[e]=pos ; ssrc[pos]=src[e] ; sdst[pos]=dst
__global__ __launch_bounds__(256, 4) void scatter_kernel(
    const int* __restrict__ srcs, const int* __restrict__ dsts,
    int* __restrict__ cursor, int* __restrict__ inv,
    int* __restrict__ ssrc, int* __restrict__ sdst)
{
    for (int e = blockIdx.x * 256 + threadIdx.x; e < N_EDGES;
         e += gridDim.x * 256) {
        const int d = dsts[e];
        const int pos = atomicAdd(&cursor[d], 1);
        inv[e] = pos;
        ssrc[pos] = srcs[e];
        sdst[pos] = d;
    }
}

// ---------------------------------------------------------------------------
// h0 = x @ node_W + node_b      [N,128]@[128,64]; also fp16 copy for gathers
// ---------------------------------------------------------------------------
__global__ __launch_bounds__(256, 2) void node_proj_kernel(
    const float* __restrict__ x, const float* __restrict__ W,
    const float* __restrict__ b, float* __restrict__ h, __half* __restrict__ zh)
{
    __shared__ float xs[4][IN_DIM];
    const int c = threadIdx.x & 63;
    const int local_n = threadIdx.x >> 6;
    float w[IN_DIM];
#pragma unroll
    for (int k = 0; k < IN_DIM; ++k) w[k] = W[k * HID + c];
    const float bias = b[c];

    for (int base = blockIdx.x * 4; base < N_NODES; base += gridDim.x * 4) {
        __syncthreads();
#pragma unroll
        for (int i = 0; i < 2; ++i) {
            int idx = threadIdx.x + i * 256;
            int nn = idx >> 7, kk = idx & 127;
            xs[nn][kk] = x[(base + nn) * IN_DIM + kk];
        }
        __syncthreads();
        const int n = base + local_n;
        float acc = bias;
#pragma unroll
        for (int k4 = 0; k4 < IN_DIM / 4; ++k4) {
            float4 xv = ((const float4*)xs[local_n])[k4];
            acc = fmaf(xv.x, w[k4 * 4 + 0], acc);
            acc = fmaf(xv.y, w[k4 * 4 + 1], acc);
            acc = fmaf(xv.z, w[k4 * 4 + 2], acc);
            acc = fmaf(xv.w, w[k4 * 4 + 3], acc);
        }
        h[n * HID + c] = acc;
        zh[n * HID + c] = __float2half(acc);
    }
}

// ---------------------------------------------------------------------------
// edge embedding via MFMA (16 edges/wave, K padded 16->32), LDS transpose,
// contiguous 128B store per edge at eah[inv[e]].
// ---------------------------------------------------------------------------
__global__ __launch_bounds__(256, 4) void edge_emb_kernel(
    const float* __restrict__ ea, const float* __restrict__ W,
    const float* __restrict__ b, const int* __restrict__ inv,
    __half* __restrict__ eah)
{
    __shared__ __half lds_t[4][16 * HID];            // 2KB per wave
    const int lane = threadIdx.x & 63;
    const int waveid = threadIdx.x >> 6;
    const int wave = (blockIdx.x * 256 + threadIdx.x) >> 6;
    const int nwaves = gridDim.x * 4;
    const int m = lane & 15, q = lane >> 4;
    const int NT = N_EDGES / 16;                     // 50000

    half8 bf[4];
#pragma unroll
    for (int blk = 0; blk < 4; ++blk) {
#pragma unroll
        for (int i = 0; i < 8; ++i) {
            const int k = q * 8 + i;
            bf[blk][i] = (k < EDGE_DIM)
                ? (_Float16)W[k * HID + blk * 16 + m] : (_Float16)0.f;
        }
    }
    float bv[4];
#pragma unroll
    for (int blk = 0; blk < 4; ++blk) bv[blk] = b[blk * 16 + m];

    const int ed = lane >> 3, ch = lane & 7;         // store mapping

    for (int tile = wave; tile < NT; tile += nwaves) {
        const int e0 = tile * 16;
        half8 af;
#pragma unroll
        for (int i = 0; i < 8; ++i) af[i] = (_Float16)0.f;
        if (q < 2) {
            const float4* ap =
                (const float4*)(ea + (size_t)(e0 + m) * EDGE_DIM + q * 8);
            const float4 lo = ap[0];
            const float4 hi = ap[1];
            af[0] = (_Float16)lo.x; af[1] = (_Float16)lo.y;
            af[2] = (_Float16)lo.z; af[3] = (_Float16)lo.w;
            af[4] = (_Float16)hi.x; af[5] = (_Float16)hi.y;
            af[6] = (_Float16)hi.z; af[7] = (_Float16)hi.w;
        }
        floatx4 c[4];
#pragma unroll
        for (int blk = 0; blk < 4; ++blk) {
            floatx4 cin = {bv[blk], bv[blk], bv[blk], bv[blk]};
            c[blk] = __builtin_amdgcn_mfma_f32_16x16x32_f16(
                af, bf[blk], cin, 0, 0, 0);
        }
#pragma unroll
        for (int blk = 0; blk < 4; ++blk)
#pragma unroll
            for (int r = 0; r < 4; ++r)
                lds_t[waveid][(q * 4 + r) * HID + blk * 16 + m] =
                    __float2half(c[blk][r]);
        const int pos0 = inv[e0 + ed];
        const int pos1 = inv[e0 + 8 + ed];
        const float4 v0 =
            *(const float4*)&lds_t[waveid][ed * HID + ch * 8];
        const float4 v1 =
            *(const float4*)&lds_t[waveid][(8 + ed) * HID + ch * 8];
        ((float4*)(eah + (size_t)pos0 * HID))[ch] = v0;
        ((float4*)(eah + (size_t)pos1 * HID))[ch] = v1;
    }
}

// ---------------------------------------------------------------------------
// Edge-major segmented softmax-aggregate, depth-2 software pipeline:
// prefetch group g+1's 8 z-gathers + 8 eah loads while computing group g.
// S/P flushed via atomics only at segment boundaries. p,s pre-zeroed.
// ---------------------------------------------------------------------------
__global__ __launch_bounds__(256, 4) void edge_agg_kernel(
    const __half* __restrict__ zh, const __half* __restrict__ eah,
    const int* __restrict__ ssrc, const int* __restrict__ sdst,
    const float* __restrict__ conv_t, int layer,
    float* __restrict__ p, float* __restrict__ s)
{
    const int lane = threadIdx.x & 63;
    const int wave = (blockIdx.x * 256 + threadIdx.x) >> 6;
    const int nwaves = gridDim.x * 4;
    const float t = conv_t[layer];
    const int NT = N_EDGES / 64;                     // 12500

    for (int tile = wave; tile < NT; tile += nwaves) {
        const int e0 = tile * 64;
        const int sv = ssrc[e0 + lane];              // 64 srcs, lane-resident
        const int dv = sdst[e0 + lane];              // 64 dsts
        const __half* erow = eah + (size_t)e0 * HID + lane;

        float za[8], ez[8], zb[8], eb[8];
#pragma unroll
        for (int k = 0; k < 8; ++k) {
            const int a = __builtin_amdgcn_readlane(sv, k);
            za[k] = __half2float(zh[(size_t)a * HID + lane]);
            ez[k] = __half2float(erow[(size_t)k * HID]);
        }
        float S = 0.f, P = 0.f;
        int cur = __builtin_amdgcn_readlane(dv, 0);
#pragma unroll
        for (int g = 0; g < 8; ++g) {
            if (g < 7) {                             // prefetch next group
#pragma unroll
                for (int k = 0; k < 8; ++k) {
                    const int a = __builtin_amdgcn_readlane(sv, (g + 1) * 8 + k);
                    zb[k] = __half2float(zh[(size_t)a * HID + lane]);
                    eb[k] = __half2float(erow[(size_t)((g + 1) * 8 + k) * HID]);
                }
            }
#pragma unroll
            for (int k = 0; k < 8; ++k) {
                const int d = __builtin_amdgcn_readlane(dv, g * 8 + k);
                if (d != cur) {                      // wave-uniform branch
                    unsafeAtomicAdd(&s[(size_t)cur * HID + lane], S);
                    unsafeAtomicAdd(&p[(size_t)cur * HID + lane], P);
                    S = 0.f; P = 0.f; cur = d;
                }
                const float m = fmaxf(za[k] + ez[k], 0.f) + 1e-7f;
                const float xx = __expf(m * t);
                S += xx;
                P = fmaf(m, xx, P);
            }
            if (g < 7) {
#pragma unroll
                for (int k = 0; k < 8; ++k) { za[k] = zb[k]; ez[k] = eb[k]; }
            }
        }
        unsafeAtomicAdd(&s[(size_t)cur * HID + lane], S);
        unsafeAtomicAdd(&p[(size_t)cur * HID + lane], P);
    }
}

// ---------------------------------------------------------------------------
// mm1: hin = p/(s+eps) + zin ; u = hin@W1 + b1 ; v = relu(LN128(u)*g1+be1)
// ---------------------------------------------------------------------------
__global__ __launch_bounds__(256, 2) void node_mm1_kernel(
    const float* __restrict__ p, const float* __restrict__ s,
    const float* __restrict__ zin,
    const float* __restrict__ W1, const float* __restrict__ b1,
    const float* __restrict__ g1, const float* __restrict__ be1,
    float* __restrict__ v)
{
    __shared__ float hs[2][HID];
    __shared__ float red[2][2][2];
    const int j = threadIdx.x & 127;
    const int local_n = threadIdx.x >> 7;
    const int wavehalf = (threadIdx.x >> 6) & 1;
    float w[HID];
#pragma unroll
    for (int k = 0; k < HID; ++k) w[k] = W1[k * HID2 + j];
    const float bias = b1[j];
    const float g = g1[j];
    const float be = be1[j];

    for (int base = blockIdx.x * 2; base < N_NODES; base += gridDim.x * 2) {
        __syncthreads();
        if (threadIdx.x < 128) {
            int nn = threadIdx.x >> 6, c = threadIdx.x & 63;
            int idx = (base + nn) * HID + c;
            hs[nn][c] = p[idx] / (s[idx] + 1e-16f) + zin[idx];
        }
        __syncthreads();
        const int n = base + local_n;
        float u = bias;
#pragma unroll
        for (int k4 = 0; k4 < HID / 4; ++k4) {
            float4 hv = ((const float4*)hs[local_n])[k4];
            u = fmaf(hv.x, w[k4 * 4 + 0], u);
            u = fmaf(hv.y, w[k4 * 4 + 1], u);
            u = fmaf(hv.z, w[k4 * 4 + 2], u);
            u = fmaf(hv.w, w[k4 * 4 + 3], u);
        }
        float ps_ = u;
#pragma unroll
        for (int o = 1; o < 64; o <<= 1) ps_ += __shfl_xor(ps_, o, 64);
        if ((threadIdx.x & 63) == 0) red[local_n][0][wavehalf] = ps_;
        __syncthreads();
        const float mu = (red[local_n][0][0] + red[local_n][0][1]) * (1.f / 128.f);
        const float d = u - mu;
        float q = d * d;
#pragma unroll
        for (int o = 1; o < 64; o <<= 1) q += __shfl_xor(q, o, 64);
        if ((threadIdx.x & 63) == 0) red[local_n][1][wavehalf] = q;
        __syncthreads();
        const float var = (red[local_n][1][0] + red[local_n][1][1]) * (1.f / 128.f);
        const float y = d * rsqrtf(var + 1e-5f) * g + be;
        v[n * HID2 + j] = y > 0.f ? y : 0.f;
    }
}

// ---------------------------------------------------------------------------
// mm2: out2 = v@W2 + b2 ; h = (residual? h:0) + out2 ;
//      z = relu(LN64(h)*gz+bz) ; zh = fp16(z)
// ---------------------------------------------------------------------------
__global__ __launch_bounds__(256, 2) void node_mm2_kernel(
    const float* __restrict__ v,
    const float* __restrict__ W2, const float* __restrict__ b2,
    const float* __restrict__ lng, const float* __restrict__ lnb,
    float* __restrict__ h, float* __restrict__ z, __half* __restrict__ zh,
    int residual)
{
    __shared__ float vs[4][HID2];
    const int c = threadIdx.x & 63;
    const int local_n = threadIdx.x >> 6;
    float w[HID2];
#pragma unroll
    for (int k = 0; k < HID2; ++k) w[k] = W2[k * HID + c];
    const float bias = b2[c];
    const float g = lng[c];
    const float be = lnb[c];

    for (int base = blockIdx.x * 4; base < N_NODES; base += gridDim.x * 4) {
        __syncthreads();
#pragma unroll
        for (int i = 0; i < 2; ++i) {
            int idx = threadIdx.x + i * 256;
            int nn = idx >> 7, kk = idx & 127;
            vs[nn][kk] = v[(base + nn) * HID2 + kk];
        }
        __syncthreads();
        const int n = base + local_n;
        float acc = bias;
#pragma unroll
        for (int k4 = 0; k4 < HID2 / 4; ++k4) {
            float4 vv = ((const float4*)vs[local_n])[k4];
            acc = fmaf(vv.x, w[k4 * 4 + 0], acc);
            acc = fmaf(vv.y, w[k4 * 4 + 1], acc);
            acc = fmaf(vv.z, w[k4 * 4 + 2], acc);
            acc = fmaf(vv.w, w[k4 * 4 + 3], acc);
        }
        const float hn = residual ? (h[n * HID + c] + acc) : acc;
        h[n * HID + c] = hn;
        float ps_ = hn;
#pragma unroll
        for (int o = 1; o < 64; o <<= 1) ps_ += __shfl_xor(ps_, o, 64);
        const float mu = ps_ * (1.f / 64.f);
        const float d = hn - mu;
        float q = d * d;
#pragma unroll
        for (int o = 1; o < 64; o <<= 1) q += __shfl_xor(q, o, 64);
        const float var = q * (1.f / 64.f);
        const float y = d * rsqrtf(var + 1e-5f) * g + be;
        const float zr = y > 0.f ? y : 0.f;
        z[n * HID + c] = zr;
        zh[n * HID + c] = __float2half(zr);
    }
}

// ---------------------------------------------------------------------------
// out = z @ lin_W + lin_b      [N,64]@[64,8]
// ---------------------------------------------------------------------------
__global__ __launch_bounds__(256, 4) void final_kernel(
    const float* __restrict__ z, const float* __restrict__ Wl,
    const float* __restrict__ bl, float* __restrict__ out)
{
    __shared__ float wl[HID * OUT_DIM];
    for (int i = threadIdx.x; i < HID * OUT_DIM; i += 256) wl[i] = Wl[i];
    __syncthreads();
    const int total = N_NODES * OUT_DIM;
    for (int idx = blockIdx.x * 256 + threadIdx.x; idx < total;
         idx += gridDim.x * 256) {
        const int n = idx >> 3, o = idx & 7;
        const float4* zp4 = (const float4*)(z + n * HID);
        float acc = bl[o];
#pragma unroll
        for (int k4 = 0; k4 < HID / 4; ++k4) {
            float4 zv = zp4[k4];
            acc = fmaf(zv.x, wl[(k4 * 4 + 0) * OUT_DIM + o], acc);
            acc = fmaf(zv.y, wl[(k4 * 4 + 1) * OUT_DIM + o], acc);
            acc = fmaf(zv.z, wl[(k4 * 4 + 2) * OUT_DIM + o], acc);
            acc = fmaf(zv.w, wl[(k4 * 4 + 3) * OUT_DIM + o], acc);
        }
        out[idx] = acc;
    }
}

// ---------------------------------------------------------------------------
extern "C" void kernel_launch(void* const* d_in, const int* in_sizes, int n_in,
                              void* d_out, int out_size, void* d_ws, size_t ws_size,
                              hipStream_t stream)
{
    const float* x         = (const float*)d_in[0];
    const float* edge_attr = (const float*)d_in[1];
    const float* node_W    = (const float*)d_in[2];
    const float* node_b    = (const float*)d_in[3];
    const float* edge_W    = (const float*)d_in[4];
    const float* edge_b    = (const float*)d_in[5];
    const float* conv_t    = (const float*)d_in[6];
    const float* conv_W1   = (const float*)d_in[7];
    const float* conv_b1   = (const float*)d_in[8];
    const float* conv_g1   = (const float*)d_in[9];
    const float* conv_be1  = (const float*)d_in[10];
    const float* conv_W2   = (const float*)d_in[11];
    const float* conv_b2   = (const float*)d_in[12];
    const float* ln_g      = (const float*)d_in[13];
    const float* ln_b      = (const float*)d_in[14];
    const float* lin_W     = (const float*)d_in[15];
    const float* lin_b     = (const float*)d_in[16];
    const int*   edge_index= (const int*)d_in[17];
    const int*   srcs = edge_index;
    const int*   dsts = edge_index + N_EDGES;
    float* out = (float*)d_out;

    // workspace layout (~173 MB)
    float* h   = (float*)d_ws;                    // N*64
    float* z   = h   + N_NODES * HID;             // N*64
    float* p   = z   + N_NODES * HID;             // N*64
    float* s   = p   + N_NODES * HID;             // N*64 (contiguous w/ p)
    float* v   = s   + N_NODES * HID;             // N*128
    __half* zh  = (__half*)(v + N_NODES * HID2);  // N*64 half
    __half* eah = zh + (size_t)N_NODES * HID;     // E*64 half
    int* deg     = (int*)(eah + (size_t)N_EDGES * HID); // N
    int* offsets = deg + N_NODES;                 // N+1
    int* cursor  = offsets + N_NODES + 1;         // N
    int* inv     = cursor + N_NODES;              // E
    int* ssrc    = inv + N_EDGES;                 // E
    int* sdst    = ssrc + N_EDGES;                // E

    // ---- counting sort of edges by dst (once per call) ----
    hipMemsetAsync(deg, 0, (size_t)N_NODES * sizeof(int), stream);
    hist_kernel<<<1024, 256, 0, stream>>>(dsts, deg);
    scan_kernel<<<1, 1024, 0, stream>>>(deg, offsets, cursor);
    scatter_kernel<<<1024, 256, 0, stream>>>(srcs, dsts, cursor, inv, ssrc, sdst);

    node_proj_kernel<<<2048, 256, 0, stream>>>(x, node_W, node_b, h, zh);
    edge_emb_kernel<<<3125, 256, 0, stream>>>(edge_attr, edge_W, edge_b, inv, eah);

    for (int layer = 0; layer < N_LAYERS; ++layer) {
        const float* zin = (layer == 0) ? h : z;
        hipMemsetAsync(p, 0, (size_t)2 * N_NODES * HID * sizeof(float), stream);
        edge_agg_kernel<<<3125, 256, 0, stream>>>(zh, eah, ssrc, sdst,
                                                  conv_t, layer, p, s);
        node_mm1_kernel<<<2048, 256, 0, stream>>>(
            p, s, zin,
            conv_W1 + (size_t)layer * HID * HID2, conv_b1 + layer * HID2,
            conv_g1 + layer * HID2, conv_be1 + layer * HID2, v);
        const float* gz = (layer < N_LAYERS - 1) ? (ln_g + (layer + 1) * HID) : ln_g;
        const float* bz = (layer < N_LAYERS - 1) ? (ln_b + (layer + 1) * HID) : ln_b;
        node_mm2_kernel<<<2048, 256, 0, stream>>>(
            v, conv_W2 + (size_t)layer * HID2 * HID, conv_b2 + layer * HID,
            gz, bz, h, z, zh, layer > 0 ? 1 : 0);
    }
    final_kernel<<<1024, 256, 0, stream>>>(z, lin_W, lin_b, out);
}

// Round 7
// 815.055 us; speedup vs baseline: 1.3882x; 1.1244x over previous
//
#include <hip/hip_runtime.h>
#include <hip/hip_fp16.h>

#define N_NODES 50000
#define N_EDGES 800000
#define IN_DIM  128
#define EDGE_DIM 16
#define HID     64
#define HID2    128
#define OUT_DIM 8
#define N_LAYERS 4
#define SCAN_BLOCKS 196   // ceil(50000/256)

typedef _Float16 half8 __attribute__((ext_vector_type(8)));
typedef float floatx4 __attribute__((ext_vector_type(4)));

// ---------------------------------------------------------------------------
// Counting sort of edges by dst: histogram -> 3-kernel parallel scan -> scatter
// ---------------------------------------------------------------------------
__global__ __launch_bounds__(256, 4) void hist_kernel(
    const int* __restrict__ dsts, int* __restrict__ deg)
{
    for (int e = blockIdx.x * 256 + threadIdx.x; e < N_EDGES;
         e += gridDim.x * 256)
        atomicAdd(&deg[dsts[e]], 1);
}

// per-block sums of deg (coalesced)
__global__ __launch_bounds__(256) void scan1_kernel(
    const int* __restrict__ deg, int* __restrict__ bsum)
{
    __shared__ int red[256];
    const int i = blockIdx.x * 256 + threadIdx.x;
    red[threadIdx.x] = (i < N_NODES) ? deg[i] : 0;
    __syncthreads();
    for (int off = 128; off > 0; off >>= 1) {
        if (threadIdx.x < off) red[threadIdx.x] += red[threadIdx.x + off];
        __syncthreads();
    }
    if (threadIdx.x == 0) bsum[blockIdx.x] = red[0];
}

// single block: exclusive scan of the 196 block sums
__global__ __launch_bounds__(256, 1) void scan2_kernel(
    const int* __restrict__ bsum, int* __restrict__ bbase)
{
    __shared__ int part[256];
    const int t = threadIdx.x;
    int v = (t < SCAN_BLOCKS) ? bsum[t] : 0;
    part[t] = v;
    __syncthreads();
    for (int off = 1; off < 256; off <<= 1) {
        int x = (t >= off) ? part[t - off] : 0;
        __syncthreads();
        part[t] += x;
        __syncthreads();
    }
    bbase[t] = (t > 0) ? part[t - 1] : 0;
}

// per-block local exclusive scan + block base -> cursor
__global__ __launch_bounds__(256) void scan3_kernel(
    const int* __restrict__ deg, const int* __restrict__ bbase,
    int* __restrict__ cursor)
{
    __shared__ int part[256];
    const int t = threadIdx.x;
    const int i = blockIdx.x * 256 + t;
    const int v = (i < N_NODES) ? deg[i] : 0;
    part[t] = v;
    __syncthreads();
    for (int off = 1; off < 256; off <<= 1) {
        int x = (t >= off) ? part[t - off] : 0;
        __syncthreads();
        part[t] += x;
        __syncthreads();
    }
    if (i < N_NODES) cursor[i] = part[t] - v + bbase[blockIdx.x];
}

// pos = cursor[dst]++ ; inv[e]=pos ; ssrc[pos]=src[e] ; sdst[pos]=dst
__global__ __launch_bounds__(256, 4) void scatter_kernel(
    const int* __restrict__ srcs, const int* __restrict__ dsts,
    int* __restrict__ cursor, int* __restrict__ inv,
    int* __restrict__ ssrc, int* __restrict__ sdst)
{
    for (int e = blockIdx.x * 256 + threadIdx.x; e < N_EDGES;
         e += gridDim.x * 256) {
        const int d = dsts[e];
        const int pos = atomicAdd(&cursor[d], 1);
        inv[e] = pos;
        ssrc[pos] = srcs[e];
        sdst[pos] = d;
    }
}

// ---------------------------------------------------------------------------
// h0 = x @ node_W + node_b      [N,128]@[128,64]; also fp16 copy for gathers
// ---------------------------------------------------------------------------
__global__ __launch_bounds__(256, 2) void node_proj_kernel(
    const float* __restrict__ x, const float* __restrict__ W,
    const float* __restrict__ b, float* __restrict__ h, __half* __restrict__ zh)
{
    __shared__ float xs[4][IN_DIM];
    const int c = threadIdx.x & 63;
    const int local_n = threadIdx.x >> 6;
    float w[IN_DIM];
#pragma unroll
    for (int k = 0; k < IN_DIM; ++k) w[k] = W[k * HID + c];
    const float bias = b[c];

    for (int base = blockIdx.x * 4; base < N_NODES; base += gridDim.x * 4) {
        __syncthreads();
#pragma unroll
        for (int i = 0; i < 2; ++i) {
            int idx = threadIdx.x + i * 256;
            int nn = idx >> 7, kk = idx & 127;
            xs[nn][kk] = x[(base + nn) * IN_DIM + kk];
        }
        __syncthreads();
        const int n = base + local_n;
        float acc = bias;
#pragma unroll
        for (int k4 = 0; k4 < IN_DIM / 4; ++k4) {
            float4 xv = ((const float4*)xs[local_n])[k4];
            acc = fmaf(xv.x, w[k4 * 4 + 0], acc);
            acc = fmaf(xv.y, w[k4 * 4 + 1], acc);
            acc = fmaf(xv.z, w[k4 * 4 + 2], acc);
            acc = fmaf(xv.w, w[k4 * 4 + 3], acc);
        }
        h[n * HID + c] = acc;
        zh[n * HID + c] = __float2half(acc);
    }
}

// ---------------------------------------------------------------------------
// edge embedding via MFMA (16 edges/wave, K padded 16->32), LDS transpose,
// contiguous 128B store per edge at eah[inv[e]].
// ---------------------------------------------------------------------------
__global__ __launch_bounds__(256, 4) void edge_emb_kernel(
    const float* __restrict__ ea, const float* __restrict__ W,
    const float* __restrict__ b, const int* __restrict__ inv,
    __half* __restrict__ eah)
{
    __shared__ __half lds_t[4][16 * HID];            // 2KB per wave
    const int lane = threadIdx.x & 63;
    const int waveid = threadIdx.x >> 6;
    const int wave = (blockIdx.x * 256 + threadIdx.x) >> 6;
    const int nwaves = gridDim.x * 4;
    const int m = lane & 15, q = lane >> 4;
    const int NT = N_EDGES / 16;                     // 50000

    half8 bf[4];
#pragma unroll
    for (int blk = 0; blk < 4; ++blk) {
#pragma unroll
        for (int i = 0; i < 8; ++i) {
            const int k = q * 8 + i;
            bf[blk][i] = (k < EDGE_DIM)
                ? (_Float16)W[k * HID + blk * 16 + m] : (_Float16)0.f;
        }
    }
    float bv[4];
#pragma unroll
    for (int blk = 0; blk < 4; ++blk) bv[blk] = b[blk * 16 + m];

    const int ed = lane >> 3, ch = lane & 7;         // store mapping

    for (int tile = wave; tile < NT; tile += nwaves) {
        const int e0 = tile * 16;
        half8 af;
#pragma unroll
        for (int i = 0; i < 8; ++i) af[i] = (_Float16)0.f;
        if (q < 2) {
            const float4* ap =
                (const float4*)(ea + (size_t)(e0 + m) * EDGE_DIM + q * 8);
            const float4 lo = ap[0];
            const float4 hi = ap[1];
            af[0] = (_Float16)lo.x; af[1] = (_Float16)lo.y;
            af[2] = (_Float16)lo.z; af[3] = (_Float16)lo.w;
            af[4] = (_Float16)hi.x; af[5] = (_Float16)hi.y;
            af[6] = (_Float16)hi.z; af[7] = (_Float16)hi.w;
        }
        floatx4 c[4];
#pragma unroll
        for (int blk = 0; blk < 4; ++blk) {
            floatx4 cin = {bv[blk], bv[blk], bv[blk], bv[blk]};
            c[blk] = __builtin_amdgcn_mfma_f32_16x16x32_f16(
                af, bf[blk], cin, 0, 0, 0);
        }
#pragma unroll
        for (int blk = 0; blk < 4; ++blk)
#pragma unroll
            for (int r = 0; r < 4; ++r)
                lds_t[waveid][(q * 4 + r) * HID + blk * 16 + m] =
                    __float2half(c[blk][r]);
        const int pos0 = inv[e0 + ed];
        const int pos1 = inv[e0 + 8 + ed];
        const float4 v0 =
            *(const float4*)&lds_t[waveid][ed * HID + ch * 8];
        const float4 v1 =
            *(const float4*)&lds_t[waveid][(8 + ed) * HID + ch * 8];
        ((float4*)(eah + (size_t)pos0 * HID))[ch] = v0;
        ((float4*)(eah + (size_t)pos1 * HID))[ch] = v1;
    }
}

// ---------------------------------------------------------------------------
// Edge-major segmented softmax-aggregate.
//  - boundary detection once per tile via shfl_up + ballot -> SALU bit tests
//  - z-gathers via uniform SGPR base (readlane src) + lane voffset
//  - f16 add/relu, single cvt, exp2 with prescaled t
// p,s zeroed before layer 0 by memset, then re-zeroed by mm1 each layer.
// ---------------------------------------------------------------------------
__global__ __launch_bounds__(256, 4) void edge_agg_kernel(
    const __half* __restrict__ zh, const __half* __restrict__ eah,
    const int* __restrict__ ssrc, const int* __restrict__ sdst,
    const float* __restrict__ conv_t, int layer,
    float* __restrict__ p, float* __restrict__ s)
{
    const int lane = threadIdx.x & 63;
    const int wave = (blockIdx.x * 256 + threadIdx.x) >> 6;
    const int nwaves = gridDim.x * 4;
    const float t2 = conv_t[layer] * 1.4426950408889634f;  // log2(e)*t
    const int NT = N_EDGES / 64;                     // 12500

    const _Float16* zf = (const _Float16*)zh;
    const _Float16* ef = (const _Float16*)eah;

    for (int tile = wave; tile < NT; tile += nwaves) {
        const int e0 = tile * 64;
        const int sv = ssrc[e0 + lane];              // 64 srcs, lane-resident
        const int dv = sdst[e0 + lane];              // 64 dsts
        const int pv = __shfl_up(dv, 1, 64);
        const unsigned long long bmask = __ballot(dv != pv) & ~1ull;
        const _Float16* erow = ef + (size_t)e0 * HID + lane;

        float S = 0.f, P = 0.f;
        int cur = __builtin_amdgcn_readlane(dv, 0);
#pragma unroll
        for (int g = 0; g < 8; ++g) {
            _Float16 zH[8], eH[8];
#pragma unroll
            for (int k = 0; k < 8; ++k) {
                const int a = __builtin_amdgcn_readlane(sv, g * 8 + k);
                const _Float16* rp = zf + (size_t)a * HID;   // uniform base
                zH[k] = rp[lane];
                eH[k] = erow[(size_t)(g * 8 + k) * HID];
            }
#pragma unroll
            for (int k = 0; k < 8; ++k) {
                const int j = g * 8 + k;
                if (bmask & (1ull << j)) {           // SALU test, uniform
                    unsafeAtomicAdd(&s[(size_t)cur * HID + lane], S);
                    unsafeAtomicAdd(&p[(size_t)cur * HID + lane], P);
                    S = 0.f; P = 0.f;
                    cur = __builtin_amdgcn_readlane(dv, j);
                }
                _Float16 mh = zH[k] + eH[k];
                mh = mh > (_Float16)0.f ? mh : (_Float16)0.f;
                const float m = (float)mh + 1e-7f;
                const float xx = __builtin_amdgcn_exp2f(m * t2);
                S += xx;
                P = fmaf(m, xx, P);
            }
        }
        unsafeAtomicAdd(&s[(size_t)cur * HID + lane], S);
        unsafeAtomicAdd(&p[(size_t)cur * HID + lane], P);
    }
}

// ---------------------------------------------------------------------------
// mm1: hin = p/(s+eps) + zin ; u = hin@W1 + b1 ; v = relu(LN128(u)*g1+be1)
// Also re-zeroes p,s for the next layer's aggregation.
// ---------------------------------------------------------------------------
__global__ __launch_bounds__(256, 2) void node_mm1_kernel(
    float* __restrict__ p, float* __restrict__ s,
    const float* __restrict__ zin,
    const float* __restrict__ W1, const float* __restrict__ b1,
    const float* __restrict__ g1, const float* __restrict__ be1,
    float* __restrict__ v)
{
    __shared__ float hs[2][HID];
    __shared__ float red[2][2][2];
    const int j = threadIdx.x & 127;
    const int local_n = threadIdx.x >> 7;
    const int wavehalf = (threadIdx.x >> 6) & 1;
    float w[HID];
#pragma unroll
    for (int k = 0; k < HID; ++k) w[k] = W1[k * HID2 + j];
    const float bias = b1[j];
    const float g = g1[j];
    const float be = be1[j];

    for (int base = blockIdx.x * 2; base < N_NODES; base += gridDim.x * 2) {
        __syncthreads();
        if (threadIdx.x < 128) {
            int nn = threadIdx.x >> 6, c = threadIdx.x & 63;
            int idx = (base + nn) * HID + c;
            hs[nn][c] = p[idx] / (s[idx] + 1e-16f) + zin[idx];
            p[idx] = 0.f;                            // re-zero for next layer
            s[idx] = 0.f;
        }
        __syncthreads();
        const int n = base + local_n;
        float u = bias;
#pragma unroll
        for (int k4 = 0; k4 < HID / 4; ++k4) {
            float4 hv = ((const float4*)hs[local_n])[k4];
            u = fmaf(hv.x, w[k4 * 4 + 0], u);
            u = fmaf(hv.y, w[k4 * 4 + 1], u);
            u = fmaf(hv.z, w[k4 * 4 + 2], u);
            u = fmaf(hv.w, w[k4 * 4 + 3], u);
        }
        float ps_ = u;
#pragma unroll
        for (int o = 1; o < 64; o <<= 1) ps_ += __shfl_xor(ps_, o, 64);
        if ((threadIdx.x & 63) == 0) red[local_n][0][wavehalf] = ps_;
        __syncthreads();
        const float mu = (red[local_n][0][0] + red[local_n][0][1]) * (1.f / 128.f);
        const float d = u - mu;
        float q = d * d;
#pragma unroll
        for (int o = 1; o < 64; o <<= 1) q += __shfl_xor(q, o, 64);
        if ((threadIdx.x & 63) == 0) red[local_n][1][wavehalf] = q;
        __syncthreads();
        const float var = (red[local_n][1][0] + red[local_n][1][1]) * (1.f / 128.f);
        const float y = d * rsqrtf(var + 1e-5f) * g + be;
        v[n * HID2 + j] = y > 0.f ? y : 0.f;
    }
}

// ---------------------------------------------------------------------------
// mm2: out2 = v@W2 + b2 ; h = (residual? h:0) + out2 ;
//      z = relu(LN64(h)*gz+bz) ; zh = fp16(z)
// ---------------------------------------------------------------------------
__global__ __launch_bounds__(256, 2) void node_mm2_kernel(
    const float* __restrict__ v,
    const float* __restrict__ W2, const float* __restrict__ b2,
    const float* __restrict__ lng, const float* __restrict__ lnb,
    float* __restrict__ h, float* __restrict__ z, __half* __restrict__ zh,
    int residual)
{
    __shared__ float vs[4][HID2];
    const int c = threadIdx.x & 63;
    const int local_n = threadIdx.x >> 6;
    float w[HID2];
#pragma unroll
    for (int k = 0; k < HID2; ++k) w[k] = W2[k * HID + c];
    const float bias = b2[c];
    const float g = lng[c];
    const float be = lnb[c];

    for (int base = blockIdx.x * 4; base < N_NODES; base += gridDim.x * 4) {
        __syncthreads();
#pragma unroll
        for (int i = 0; i < 2; ++i) {
            int idx = threadIdx.x + i * 256;
            int nn = idx >> 7, kk = idx & 127;
            vs[nn][kk] = v[(base + nn) * HID2 + kk];
        }
        __syncthreads();
        const int n = base + local_n;
        float acc = bias;
#pragma unroll
        for (int k4 = 0; k4 < HID2 / 4; ++k4) {
            float4 vv = ((const float4*)vs[local_n])[k4];
            acc = fmaf(vv.x, w[k4 * 4 + 0], acc);
            acc = fmaf(vv.y, w[k4 * 4 + 1], acc);
            acc = fmaf(vv.z, w[k4 * 4 + 2], acc);
            acc = fmaf(vv.w, w[k4 * 4 + 3], acc);
        }
        const float hn = residual ? (h[n * HID + c] + acc) : acc;
        h[n * HID + c] = hn;
        float ps_ = hn;
#pragma unroll
        for (int o = 1; o < 64; o <<= 1) ps_ += __shfl_xor(ps_, o, 64);
        const float mu = ps_ * (1.f / 64.f);
        const float d = hn - mu;
        float q = d * d;
#pragma unroll
        for (int o = 1; o < 64; o <<= 1) q += __shfl_xor(q, o, 64);
        const float var = q * (1.f / 64.f);
        const float y = d * rsqrtf(var + 1e-5f) * g + be;
        const float zr = y > 0.f ? y : 0.f;
        z[n * HID + c] = zr;
        zh[n * HID + c] = __float2half(zr);
    }
}

// ---------------------------------------------------------------------------
// out = z @ lin_W + lin_b      [N,64]@[64,8]
// ---------------------------------------------------------------------------
__global__ __launch_bounds__(256, 4) void final_kernel(
    const float* __restrict__ z, const float* __restrict__ Wl,
    const float* __restrict__ bl, float* __restrict__ out)
{
    __shared__ float wl[HID * OUT_DIM];
    for (int i = threadIdx.x; i < HID * OUT_DIM; i += 256) wl[i] = Wl[i];
    __syncthreads();
    const int total = N_NODES * OUT_DIM;
    for (int idx = blockIdx.x * 256 + threadIdx.x; idx < total;
         idx += gridDim.x * 256) {
        const int n = idx >> 3, o = idx & 7;
        const float4* zp4 = (const float4*)(z + n * HID);
        float acc = bl[o];
#pragma unroll
        for (int k4 = 0; k4 < HID / 4; ++k4) {
            float4 zv = zp4[k4];
            acc = fmaf(zv.x, wl[(k4 * 4 + 0) * OUT_DIM + o], acc);
            acc = fmaf(zv.y, wl[(k4 * 4 + 1) * OUT_DIM + o], acc);
            acc = fmaf(zv.z, wl[(k4 * 4 + 2) * OUT_DIM + o], acc);
            acc = fmaf(zv.w, wl[(k4 * 4 + 3) * OUT_DIM + o], acc);
        }
        out[idx] = acc;
    }
}

// ---------------------------------------------------------------------------
extern "C" void kernel_launch(void* const* d_in, const int* in_sizes, int n_in,
                              void* d_out, int out_size, void* d_ws, size_t ws_size,
                              hipStream_t stream)
{
    const float* x         = (const float*)d_in[0];
    const float* edge_attr = (const float*)d_in[1];
    const float* node_W    = (const float*)d_in[2];
    const float* node_b    = (const float*)d_in[3];
    const float* edge_W    = (const float*)d_in[4];
    const float* edge_b    = (const float*)d_in[5];
    const float* conv_t    = (const float*)d_in[6];
    const float* conv_W1   = (const float*)d_in[7];
    const float* conv_b1   = (const float*)d_in[8];
    const float* conv_g1   = (const float*)d_in[9];
    const float* conv_be1  = (const float*)d_in[10];
    const float* conv_W2   = (const float*)d_in[11];
    const float* conv_b2   = (const float*)d_in[12];
    const float* ln_g      = (const float*)d_in[13];
    const float* ln_b      = (const float*)d_in[14];
    const float* lin_W     = (const float*)d_in[15];
    const float* lin_b     = (const float*)d_in[16];
    const int*   edge_index= (const int*)d_in[17];
    const int*   srcs = edge_index;
    const int*   dsts = edge_index + N_EDGES;
    float* out = (float*)d_out;

    // workspace layout (~173 MB)
    float* h   = (float*)d_ws;                    // N*64
    float* z   = h   + N_NODES * HID;             // N*64
    float* p   = z   + N_NODES * HID;             // N*64
    float* s   = p   + N_NODES * HID;             // N*64 (contiguous w/ p)
    float* v   = s   + N_NODES * HID;             // N*128
    __half* zh  = (__half*)(v + N_NODES * HID2);  // N*64 half
    __half* eah = zh + (size_t)N_NODES * HID;     // E*64 half
    int* deg     = (int*)(eah + (size_t)N_EDGES * HID); // N
    int* cursor  = deg + N_NODES;                 // N
    int* bsum    = cursor + N_NODES;              // 256
    int* bbase   = bsum + 256;                    // 256
    int* inv     = bbase + 256;                   // E
    int* ssrc    = inv + N_EDGES;                 // E
    int* sdst    = ssrc + N_EDGES;                // E

    // ---- counting sort of edges by dst (once per call) ----
    hipMemsetAsync(deg, 0, (size_t)N_NODES * sizeof(int), stream);
    hist_kernel<<<1024, 256, 0, stream>>>(dsts, deg);
    scan1_kernel<<<SCAN_BLOCKS, 256, 0, stream>>>(deg, bsum);
    scan2_kernel<<<1, 256, 0, stream>>>(bsum, bbase);
    scan3_kernel<<<SCAN_BLOCKS, 256, 0, stream>>>(deg, bbase, cursor);
    scatter_kernel<<<1024, 256, 0, stream>>>(srcs, dsts, cursor, inv, ssrc, sdst);

    node_proj_kernel<<<2048, 256, 0, stream>>>(x, node_W, node_b, h, zh);
    edge_emb_kernel<<<3125, 256, 0, stream>>>(edge_attr, edge_W, edge_b, inv, eah);

    // zero p,s once; node_mm1 re-zeroes them for the next layer
    hipMemsetAsync(p, 0, (size_t)2 * N_NODES * HID * sizeof(float), stream);

    for (int layer = 0; layer < N_LAYERS; ++layer) {
        const float* zin = (layer == 0) ? h : z;
        edge_agg_kernel<<<3125, 256, 0, stream>>>(zh, eah, ssrc, sdst,
                                                  conv_t, layer, p, s);
        node_mm1_kernel<<<2048, 256, 0, stream>>>(
            p, s, zin,
            conv_W1 + (size_t)layer * HID * HID2, conv_b1 + layer * HID2,
            conv_g1 + layer * HID2, conv_be1 + layer * HID2, v);
        const float* gz = (layer < N_LAYERS - 1) ? (ln_g + (layer + 1) * HID) : ln_g;
        const float* bz = (layer < N_LAYERS - 1) ? (ln_b + (layer + 1) * HID) : ln_b;
        node_mm2_kernel<<<2048, 256, 0, stream>>>(
            v, conv_W2 + (size_t)layer * HID2 * HID, conv_b2 + layer * HID,
            gz, bz, h, z, zh, layer > 0 ? 1 : 0);
    }
    final_kernel<<<1024, 256, 0, stream>>>(z, lin_W, lin_b, out);
}

// Round 8
// 800.929 us; speedup vs baseline: 1.4127x; 1.0176x over previous
//
#include <hip/hip_runtime.h>
#include <hip/hip_fp16.h>

#define N_NODES 50000
#define N_EDGES 800000
#define IN_DIM  128
#define EDGE_DIM 16
#define HID     64
#define HID2    128
#define OUT_DIM 8
#define N_LAYERS 4
#define SCAN_BLOCKS 196   // ceil(50000/256)

typedef _Float16 half8 __attribute__((ext_vector_type(8)));
typedef float floatx4 __attribute__((ext_vector_type(4)));

// ---------------------------------------------------------------------------
// Counting sort of edges by dst: histogram -> 3-kernel parallel scan -> scatter
// ---------------------------------------------------------------------------
__global__ __launch_bounds__(256, 4) void hist_kernel(
    const int* __restrict__ dsts, int* __restrict__ deg)
{
    for (int e = blockIdx.x * 256 + threadIdx.x; e < N_EDGES;
         e += gridDim.x * 256)
        atomicAdd(&deg[dsts[e]], 1);
}

__global__ __launch_bounds__(256) void scan1_kernel(
    const int* __restrict__ deg, int* __restrict__ bsum)
{
    __shared__ int red[256];
    const int i = blockIdx.x * 256 + threadIdx.x;
    red[threadIdx.x] = (i < N_NODES) ? deg[i] : 0;
    __syncthreads();
    for (int off = 128; off > 0; off >>= 1) {
        if (threadIdx.x < off) red[threadIdx.x] += red[threadIdx.x + off];
        __syncthreads();
    }
    if (threadIdx.x == 0) bsum[blockIdx.x] = red[0];
}

__global__ __launch_bounds__(256, 1) void scan2_kernel(
    const int* __restrict__ bsum, int* __restrict__ bbase)
{
    __shared__ int part[256];
    const int t = threadIdx.x;
    int v = (t < SCAN_BLOCKS) ? bsum[t] : 0;
    part[t] = v;
    __syncthreads();
    for (int off = 1; off < 256; off <<= 1) {
        int x = (t >= off) ? part[t - off] : 0;
        __syncthreads();
        part[t] += x;
        __syncthreads();
    }
    bbase[t] = (t > 0) ? part[t - 1] : 0;
}

__global__ __launch_bounds__(256) void scan3_kernel(
    const int* __restrict__ deg, const int* __restrict__ bbase,
    int* __restrict__ cursor)
{
    __shared__ int part[256];
    const int t = threadIdx.x;
    const int i = blockIdx.x * 256 + t;
    const int v = (i < N_NODES) ? deg[i] : 0;
    part[t] = v;
    __syncthreads();
    for (int off = 1; off < 256; off <<= 1) {
        int x = (t >= off) ? part[t - off] : 0;
        __syncthreads();
        part[t] += x;
        __syncthreads();
    }
    if (i < N_NODES) cursor[i] = part[t] - v + bbase[blockIdx.x];
}

// pos = cursor[dst]++ ; inv[e]=pos (coalesced) ; sd[pos]={src,dst} (one 8B line)
__global__ __launch_bounds__(256, 4) void scatter_kernel(
    const int* __restrict__ srcs, const int* __restrict__ dsts,
    int* __restrict__ cursor, int* __restrict__ inv, int2* __restrict__ sd)
{
    for (int e = blockIdx.x * 256 + threadIdx.x; e < N_EDGES;
         e += gridDim.x * 256) {
        const int d = dsts[e];
        const int pos = atomicAdd(&cursor[d], 1);
        inv[e] = pos;
        sd[pos] = make_int2(srcs[e], d);
    }
}

// ---------------------------------------------------------------------------
// h0 = x @ node_W + node_b      [N,128]@[128,64]; also fp16 copy for gathers
// ---------------------------------------------------------------------------
__global__ __launch_bounds__(256, 2) void node_proj_kernel(
    const float* __restrict__ x, const float* __restrict__ W,
    const float* __restrict__ b, float* __restrict__ h, __half* __restrict__ zh)
{
    __shared__ float xs[4][IN_DIM];
    const int c = threadIdx.x & 63;
    const int local_n = threadIdx.x >> 6;
    float w[IN_DIM];
#pragma unroll
    for (int k = 0; k < IN_DIM; ++k) w[k] = W[k * HID + c];
    const float bias = b[c];

    for (int base = blockIdx.x * 4; base < N_NODES; base += gridDim.x * 4) {
        __syncthreads();
#pragma unroll
        for (int i = 0; i < 2; ++i) {
            int idx = threadIdx.x + i * 256;
            int nn = idx >> 7, kk = idx & 127;
            xs[nn][kk] = x[(base + nn) * IN_DIM + kk];
        }
        __syncthreads();
        const int n = base + local_n;
        float acc = bias;
#pragma unroll
        for (int k4 = 0; k4 < IN_DIM / 4; ++k4) {
            float4 xv = ((const float4*)xs[local_n])[k4];
            acc = fmaf(xv.x, w[k4 * 4 + 0], acc);
            acc = fmaf(xv.y, w[k4 * 4 + 1], acc);
            acc = fmaf(xv.z, w[k4 * 4 + 2], acc);
            acc = fmaf(xv.w, w[k4 * 4 + 3], acc);
        }
        h[n * HID + c] = acc;
        zh[n * HID + c] = __float2half(acc);
    }
}

// ---------------------------------------------------------------------------
// edge embedding via MFMA (16 edges/wave, K padded 16->32), LDS transpose,
// contiguous 128B store per edge at eah[inv[e]].
// ---------------------------------------------------------------------------
__global__ __launch_bounds__(256, 4) void edge_emb_kernel(
    const float* __restrict__ ea, const float* __restrict__ W,
    const float* __restrict__ b, const int* __restrict__ inv,
    __half* __restrict__ eah)
{
    __shared__ __half lds_t[4][16 * HID];            // 2KB per wave
    const int lane = threadIdx.x & 63;
    const int waveid = threadIdx.x >> 6;
    const int wave = (blockIdx.x * 256 + threadIdx.x) >> 6;
    const int nwaves = gridDim.x * 4;
    const int m = lane & 15, q = lane >> 4;
    const int NT = N_EDGES / 16;                     // 50000

    half8 bf[4];
#pragma unroll
    for (int blk = 0; blk < 4; ++blk) {
#pragma unroll
        for (int i = 0; i < 8; ++i) {
            const int k = q * 8 + i;
            bf[blk][i] = (k < EDGE_DIM)
                ? (_Float16)W[k * HID + blk * 16 + m] : (_Float16)0.f;
        }
    }
    float bv[4];
#pragma unroll
    for (int blk = 0; blk < 4; ++blk) bv[blk] = b[blk * 16 + m];

    const int ed = lane >> 3, ch = lane & 7;         // store mapping

    for (int tile = wave; tile < NT; tile += nwaves) {
        const int e0 = tile * 16;
        half8 af;
#pragma unroll
        for (int i = 0; i < 8; ++i) af[i] = (_Float16)0.f;
        if (q < 2) {
            const float4* ap =
                (const float4*)(ea + (size_t)(e0 + m) * EDGE_DIM + q * 8);
            const float4 lo = ap[0];
            const float4 hi = ap[1];
            af[0] = (_Float16)lo.x; af[1] = (_Float16)lo.y;
            af[2] = (_Float16)lo.z; af[3] = (_Float16)lo.w;
            af[4] = (_Float16)hi.x; af[5] = (_Float16)hi.y;
            af[6] = (_Float16)hi.z; af[7] = (_Float16)hi.w;
        }
        floatx4 c[4];
#pragma unroll
        for (int blk = 0; blk < 4; ++blk) {
            floatx4 cin = {bv[blk], bv[blk], bv[blk], bv[blk]};
            c[blk] = __builtin_amdgcn_mfma_f32_16x16x32_f16(
                af, bf[blk], cin, 0, 0, 0);
        }
#pragma unroll
        for (int blk = 0; blk < 4; ++blk)
#pragma unroll
            for (int r = 0; r < 4; ++r)
                lds_t[waveid][(q * 4 + r) * HID + blk * 16 + m] =
                    __float2half(c[blk][r]);
        const int pos0 = inv[e0 + ed];
        const int pos1 = inv[e0 + 8 + ed];
        const float4 v0 =
            *(const float4*)&lds_t[waveid][ed * HID + ch * 8];
        const float4 v1 =
            *(const float4*)&lds_t[waveid][(8 + ed) * HID + ch * 8];
        ((float4*)(eah + (size_t)pos0 * HID))[ch] = v0;
        ((float4*)(eah + (size_t)pos1 * HID))[ch] = v1;
    }
}

// ---------------------------------------------------------------------------
// Edge-major segmented softmax-aggregate (packed sd = {src,dst}).
// Boundary ballot -> SALU bit tests; z gathers via uniform SGPR base;
// f16 add/relu; exp2 with prescaled t. p,s pre-zeroed (mm1 re-zeroes).
// ---------------------------------------------------------------------------
__global__ __launch_bounds__(256, 4) void edge_agg_kernel(
    const __half* __restrict__ zh, const __half* __restrict__ eah,
    const int2* __restrict__ sd,
    const float* __restrict__ conv_t, int layer,
    float* __restrict__ p, float* __restrict__ s)
{
    const int lane = threadIdx.x & 63;
    const int wave = (blockIdx.x * 256 + threadIdx.x) >> 6;
    const int nwaves = gridDim.x * 4;
    const float t2 = conv_t[layer] * 1.4426950408889634f;  // log2(e)*t
    const int NT = N_EDGES / 64;                     // 12500

    const _Float16* zf = (const _Float16*)zh;
    const _Float16* ef = (const _Float16*)eah;

    for (int tile = wave; tile < NT; tile += nwaves) {
        const int e0 = tile * 64;
        const int2 sdv = sd[e0 + lane];              // one coalesced 8B load
        const int sv = sdv.x;
        const int dv = sdv.y;
        const int pv = __shfl_up(dv, 1, 64);
        const unsigned long long bmask = __ballot(dv != pv) & ~1ull;
        const _Float16* erow = ef + (size_t)e0 * HID + lane;

        float S = 0.f, P = 0.f;
        int cur = __builtin_amdgcn_readlane(dv, 0);
#pragma unroll
        for (int g = 0; g < 8; ++g) {
            _Float16 zH[8], eH[8];
#pragma unroll
            for (int k = 0; k < 8; ++k) {
                const int a = __builtin_amdgcn_readlane(sv, g * 8 + k);
                const _Float16* rp = zf + (size_t)a * HID;   // uniform base
                zH[k] = rp[lane];
                eH[k] = erow[(size_t)(g * 8 + k) * HID];
            }
#pragma unroll
            for (int k = 0; k < 8; ++k) {
                const int j = g * 8 + k;
                if (bmask & (1ull << j)) {           // SALU test, uniform
                    unsafeAtomicAdd(&s[(size_t)cur * HID + lane], S);
                    unsafeAtomicAdd(&p[(size_t)cur * HID + lane], P);
                    S = 0.f; P = 0.f;
                    cur = __builtin_amdgcn_readlane(dv, j);
                }
                _Float16 mh = zH[k] + eH[k];
                mh = mh > (_Float16)0.f ? mh : (_Float16)0.f;
                const float m = (float)mh + 1e-7f;
                const float xx = __builtin_amdgcn_exp2f(m * t2);
                S += xx;
                P = fmaf(m, xx, P);
            }
        }
        unsafeAtomicAdd(&s[(size_t)cur * HID + lane], S);
        unsafeAtomicAdd(&p[(size_t)cur * HID + lane], P);
    }
}

// ---------------------------------------------------------------------------
// mm1: hin = p/(s+eps) + zh ; u = hin@W1 + b1 ; vh = fp16(relu(LN128(u)*g1+be1))
// Also re-zeroes p,s for the next layer's aggregation.
// ---------------------------------------------------------------------------
__global__ __launch_bounds__(256, 2) void node_mm1_kernel(
    float* __restrict__ p, float* __restrict__ s,
    const __half* __restrict__ zh,
    const float* __restrict__ W1, const float* __restrict__ b1,
    const float* __restrict__ g1, const float* __restrict__ be1,
    __half* __restrict__ vh)
{
    __shared__ float hs[2][HID];
    __shared__ float red[2][2][2];
    const int j = threadIdx.x & 127;
    const int local_n = threadIdx.x >> 7;
    const int wavehalf = (threadIdx.x >> 6) & 1;
    float w[HID];
#pragma unroll
    for (int k = 0; k < HID; ++k) w[k] = W1[k * HID2 + j];
    const float bias = b1[j];
    const float g = g1[j];
    const float be = be1[j];

    for (int base = blockIdx.x * 2; base < N_NODES; base += gridDim.x * 2) {
        __syncthreads();
        if (threadIdx.x < 128) {
            int nn = threadIdx.x >> 6, c = threadIdx.x & 63;
            int idx = (base + nn) * HID + c;
            hs[nn][c] = p[idx] / (s[idx] + 1e-16f) + __half2float(zh[idx]);
            p[idx] = 0.f;                            // re-zero for next layer
            s[idx] = 0.f;
        }
        __syncthreads();
        const int n = base + local_n;
        float u = bias;
#pragma unroll
        for (int k4 = 0; k4 < HID / 4; ++k4) {
            float4 hv = ((const float4*)hs[local_n])[k4];
            u = fmaf(hv.x, w[k4 * 4 + 0], u);
            u = fmaf(hv.y, w[k4 * 4 + 1], u);
            u = fmaf(hv.z, w[k4 * 4 + 2], u);
            u = fmaf(hv.w, w[k4 * 4 + 3], u);
        }
        float ps_ = u;
#pragma unroll
        for (int o = 1; o < 64; o <<= 1) ps_ += __shfl_xor(ps_, o, 64);
        if ((threadIdx.x & 63) == 0) red[local_n][0][wavehalf] = ps_;
        __syncthreads();
        const float mu = (red[local_n][0][0] + red[local_n][0][1]) * (1.f / 128.f);
        const float d = u - mu;
        float q = d * d;
#pragma unroll
        for (int o = 1; o < 64; o <<= 1) q += __shfl_xor(q, o, 64);
        if ((threadIdx.x & 63) == 0) red[local_n][1][wavehalf] = q;
        __syncthreads();
        const float var = (red[local_n][1][0] + red[local_n][1][1]) * (1.f / 128.f);
        const float y = d * rsqrtf(var + 1e-5f) * g + be;
        vh[(size_t)n * HID2 + j] = __float2half(y > 0.f ? y : 0.f);
    }
}

// ---------------------------------------------------------------------------
// mm2: out2 = vh@W2 + b2 ; h = (residual? h:0) + out2 ;
//      zh = fp16(relu(LN64(h)*gz+bz))
// ---------------------------------------------------------------------------
__global__ __launch_bounds__(256, 2) void node_mm2_kernel(
    const __half* __restrict__ vh,
    const float* __restrict__ W2, const float* __restrict__ b2,
    const float* __restrict__ lng, const float* __restrict__ lnb,
    float* __restrict__ h, __half* __restrict__ zh, int residual)
{
    __shared__ float vs[4][HID2];
    const int c = threadIdx.x & 63;
    const int local_n = threadIdx.x >> 6;
    float w[HID2];
#pragma unroll
    for (int k = 0; k < HID2; ++k) w[k] = W2[k * HID + c];
    const float bias = b2[c];
    const float g = lng[c];
    const float be = lnb[c];

    for (int base = blockIdx.x * 4; base < N_NODES; base += gridDim.x * 4) {
        __syncthreads();
        {   // stage 4x128 halves -> float LDS (256 threads x half2)
            const __half2* vp = (const __half2*)(vh + (size_t)base * HID2);
            const float2 f = __half22float2(vp[threadIdx.x]);
            const int nn = threadIdx.x >> 6, kk = (threadIdx.x & 63) * 2;
            vs[nn][kk] = f.x;
            vs[nn][kk + 1] = f.y;
        }
        __syncthreads();
        const int n = base + local_n;
        float acc = bias;
#pragma unroll
        for (int k4 = 0; k4 < HID2 / 4; ++k4) {
            float4 vv = ((const float4*)vs[local_n])[k4];
            acc = fmaf(vv.x, w[k4 * 4 + 0], acc);
            acc = fmaf(vv.y, w[k4 * 4 + 1], acc);
            acc = fmaf(vv.z, w[k4 * 4 + 2], acc);
            acc = fmaf(vv.w, w[k4 * 4 + 3], acc);
        }
        const float hn = residual ? (h[n * HID + c] + acc) : acc;
        h[n * HID + c] = hn;
        float ps_ = hn;
#pragma unroll
        for (int o = 1; o < 64; o <<= 1) ps_ += __shfl_xor(ps_, o, 64);
        const float mu = ps_ * (1.f / 64.f);
        const float d = hn - mu;
        float q = d * d;
#pragma unroll
        for (int o = 1; o < 64; o <<= 1) q += __shfl_xor(q, o, 64);
        const float var = q * (1.f / 64.f);
        const float y = d * rsqrtf(var + 1e-5f) * g + be;
        zh[n * HID + c] = __float2half(y > 0.f ? y : 0.f);
    }
}

// ---------------------------------------------------------------------------
// out = zh @ lin_W + lin_b      [N,64]@[64,8]
// ---------------------------------------------------------------------------
__global__ __launch_bounds__(256, 4) void final_kernel(
    const __half* __restrict__ zh, const float* __restrict__ Wl,
    const float* __restrict__ bl, float* __restrict__ out)
{
    __shared__ float wl[HID * OUT_DIM];
    for (int i = threadIdx.x; i < HID * OUT_DIM; i += 256) wl[i] = Wl[i];
    __syncthreads();
    const int total = N_NODES * OUT_DIM;
    for (int idx = blockIdx.x * 256 + threadIdx.x; idx < total;
         idx += gridDim.x * 256) {
        const int n = idx >> 3, o = idx & 7;
        const __half2* zp = (const __half2*)(zh + (size_t)n * HID);
        float acc = bl[o];
#pragma unroll
        for (int k2 = 0; k2 < HID / 2; ++k2) {
            const float2 f = __half22float2(zp[k2]);
            acc = fmaf(f.x, wl[(k2 * 2 + 0) * OUT_DIM + o], acc);
            acc = fmaf(f.y, wl[(k2 * 2 + 1) * OUT_DIM + o], acc);
        }
        out[idx] = acc;
    }
}

// ---------------------------------------------------------------------------
extern "C" void kernel_launch(void* const* d_in, const int* in_sizes, int n_in,
                              void* d_out, int out_size, void* d_ws, size_t ws_size,
                              hipStream_t stream)
{
    const float* x         = (const float*)d_in[0];
    const float* edge_attr = (const float*)d_in[1];
    const float* node_W    = (const float*)d_in[2];
    const float* node_b    = (const float*)d_in[3];
    const float* edge_W    = (const float*)d_in[4];
    const float* edge_b    = (const float*)d_in[5];
    const float* conv_t    = (const float*)d_in[6];
    const float* conv_W1   = (const float*)d_in[7];
    const float* conv_b1   = (const float*)d_in[8];
    const float* conv_g1   = (const float*)d_in[9];
    const float* conv_be1  = (const float*)d_in[10];
    const float* conv_W2   = (const float*)d_in[11];
    const float* conv_b2   = (const float*)d_in[12];
    const float* ln_g      = (const float*)d_in[13];
    const float* ln_b      = (const float*)d_in[14];
    const float* lin_W     = (const float*)d_in[15];
    const float* lin_b     = (const float*)d_in[16];
    const int*   edge_index= (const int*)d_in[17];
    const int*   srcs = edge_index;
    const int*   dsts = edge_index + N_EDGES;
    float* out = (float*)d_out;

    // workspace layout (~160 MB)
    float* h   = (float*)d_ws;                    // N*64
    float* p   = h   + N_NODES * HID;             // N*64
    float* s   = p   + N_NODES * HID;             // N*64 (contiguous w/ p)
    __half* vh  = (__half*)(s + N_NODES * HID);   // N*128 half
    __half* zh  = vh + (size_t)N_NODES * HID2;    // N*64 half
    __half* eah = zh + (size_t)N_NODES * HID;     // E*64 half
    int* deg     = (int*)(eah + (size_t)N_EDGES * HID); // N
    int* cursor  = deg + N_NODES;                 // N
    int* bsum    = cursor + N_NODES;              // 256
    int* bbase   = bsum + 256;                    // 256
    int* inv     = bbase + 256;                   // E
    int2* sd     = (int2*)(inv + N_EDGES);        // E int2 (8B aligned)

    // ---- counting sort of edges by dst (once per call) ----
    hipMemsetAsync(deg, 0, (size_t)N_NODES * sizeof(int), stream);
    hist_kernel<<<1024, 256, 0, stream>>>(dsts, deg);
    scan1_kernel<<<SCAN_BLOCKS, 256, 0, stream>>>(deg, bsum);
    scan2_kernel<<<1, 256, 0, stream>>>(bsum, bbase);
    scan3_kernel<<<SCAN_BLOCKS, 256, 0, stream>>>(deg, bbase, cursor);
    scatter_kernel<<<1024, 256, 0, stream>>>(srcs, dsts, cursor, inv, sd);

    node_proj_kernel<<<2048, 256, 0, stream>>>(x, node_W, node_b, h, zh);
    edge_emb_kernel<<<3125, 256, 0, stream>>>(edge_attr, edge_W, edge_b, inv, eah);

    // zero p,s once; node_mm1 re-zeroes them for the next layer
    hipMemsetAsync(p, 0, (size_t)2 * N_NODES * HID * sizeof(float), stream);

    for (int layer = 0; layer < N_LAYERS; ++layer) {
        edge_agg_kernel<<<3125, 256, 0, stream>>>(zh, eah, sd,
                                                  conv_t, layer, p, s);
        node_mm1_kernel<<<2048, 256, 0, stream>>>(
            p, s, zh,
            conv_W1 + (size_t)layer * HID * HID2, conv_b1 + layer * HID2,
            conv_g1 + layer * HID2, conv_be1 + layer * HID2, vh);
        const float* gz = (layer < N_LAYERS - 1) ? (ln_g + (layer + 1) * HID) : ln_g;
        const float* bz = (layer < N_LAYERS - 1) ? (ln_b + (layer + 1) * HID) : ln_b;
        node_mm2_kernel<<<2048, 256, 0, stream>>>(
            vh, conv_W2 + (size_t)layer * HID2 * HID, conv_b2 + layer * HID,
            gz, bz, h, zh, layer > 0 ? 1 : 0);
    }
    final_kernel<<<1024, 256, 0, stream>>>(zh, lin_W, lin_b, out);
}

// Round 9
// 795.346 us; speedup vs baseline: 1.4226x; 1.0070x over previous
//
#include <hip/hip_runtime.h>
#include <hip/hip_fp16.h>

#define N_NODES 50000
#define N_EDGES 800000
#define IN_DIM  128
#define EDGE_DIM 16
#define HID     64
#define HID2    128
#define OUT_DIM 8
#define N_LAYERS 4
#define SCAN_BLOCKS 196   // ceil(50000/256)

typedef _Float16 half8 __attribute__((ext_vector_type(8)));
typedef float floatx4 __attribute__((ext_vector_type(4)));

// ---------------------------------------------------------------------------
// Counting sort of edges by dst: histogram -> 3-kernel parallel scan -> scatter
// 1 edge per thread (3125 blocks): single-depth latency chain, TLP hides it.
// ---------------------------------------------------------------------------
__global__ __launch_bounds__(256, 4) void hist_kernel(
    const int* __restrict__ dsts, int* __restrict__ deg)
{
    const int e = blockIdx.x * 256 + threadIdx.x;
    atomicAdd(&deg[dsts[e]], 1);
}

__global__ __launch_bounds__(256) void scan1_kernel(
    const int* __restrict__ deg, int* __restrict__ bsum)
{
    __shared__ int red[256];
    const int i = blockIdx.x * 256 + threadIdx.x;
    red[threadIdx.x] = (i < N_NODES) ? deg[i] : 0;
    __syncthreads();
    for (int off = 128; off > 0; off >>= 1) {
        if (threadIdx.x < off) red[threadIdx.x] += red[threadIdx.x + off];
        __syncthreads();
    }
    if (threadIdx.x == 0) bsum[blockIdx.x] = red[0];
}

__global__ __launch_bounds__(256, 1) void scan2_kernel(
    const int* __restrict__ bsum, int* __restrict__ bbase)
{
    __shared__ int part[256];
    const int t = threadIdx.x;
    int v = (t < SCAN_BLOCKS) ? bsum[t] : 0;
    part[t] = v;
    __syncthreads();
    for (int off = 1; off < 256; off <<= 1) {
        int x = (t >= off) ? part[t - off] : 0;
        __syncthreads();
        part[t] += x;
        __syncthreads();
    }
    bbase[t] = (t > 0) ? part[t - 1] : 0;
}

__global__ __launch_bounds__(256) void scan3_kernel(
    const int* __restrict__ deg, const int* __restrict__ bbase,
    int* __restrict__ cursor)
{
    __shared__ int part[256];
    const int t = threadIdx.x;
    const int i = blockIdx.x * 256 + t;
    const int v = (i < N_NODES) ? deg[i] : 0;
    part[t] = v;
    __syncthreads();
    for (int off = 1; off < 256; off <<= 1) {
        int x = (t >= off) ? part[t - off] : 0;
        __syncthreads();
        part[t] += x;
        __syncthreads();
    }
    if (i < N_NODES) cursor[i] = part[t] - v + bbase[blockIdx.x];
}

// pos = cursor[dst]++ ; inv[e]=pos (coalesced) ; sd[pos]={src,dst}
__global__ __launch_bounds__(256, 4) void scatter_kernel(
    const int* __restrict__ srcs, const int* __restrict__ dsts,
    int* __restrict__ cursor, int* __restrict__ inv, int2* __restrict__ sd)
{
    const int e = blockIdx.x * 256 + threadIdx.x;
    const int d = dsts[e];
    const int pos = atomicAdd(&cursor[d], 1);
    inv[e] = pos;
    sd[pos] = make_int2(srcs[e], d);
}

// ---------------------------------------------------------------------------
// h0 = x @ node_W + node_b      [N,128]@[128,64]; also fp16 copy for gathers
// ---------------------------------------------------------------------------
__global__ __launch_bounds__(256, 2) void node_proj_kernel(
    const float* __restrict__ x, const float* __restrict__ W,
    const float* __restrict__ b, float* __restrict__ h, __half* __restrict__ zh)
{
    __shared__ float xs[4][IN_DIM];
    const int c = threadIdx.x & 63;
    const int local_n = threadIdx.x >> 6;
    float w[IN_DIM];
#pragma unroll
    for (int k = 0; k < IN_DIM; ++k) w[k] = W[k * HID + c];
    const float bias = b[c];

    for (int base = blockIdx.x * 4; base < N_NODES; base += gridDim.x * 4) {
        __syncthreads();
#pragma unroll
        for (int i = 0; i < 2; ++i) {
            int idx = threadIdx.x + i * 256;
            int nn = idx >> 7, kk = idx & 127;
            xs[nn][kk] = x[(base + nn) * IN_DIM + kk];
        }
        __syncthreads();
        const int n = base + local_n;
        float acc = bias;
#pragma unroll
        for (int k4 = 0; k4 < IN_DIM / 4; ++k4) {
            float4 xv = ((const float4*)xs[local_n])[k4];
            acc = fmaf(xv.x, w[k4 * 4 + 0], acc);
            acc = fmaf(xv.y, w[k4 * 4 + 1], acc);
            acc = fmaf(xv.z, w[k4 * 4 + 2], acc);
            acc = fmaf(xv.w, w[k4 * 4 + 3], acc);
        }
        h[n * HID + c] = acc;
        zh[n * HID + c] = __float2half(acc);
    }
}

// ---------------------------------------------------------------------------
// edge embedding via MFMA (16 edges/wave, K padded 16->32), LDS transpose,
// contiguous 128B store per edge at eah[inv[e]].
// ---------------------------------------------------------------------------
__global__ __launch_bounds__(256, 4) void edge_emb_kernel(
    const float* __restrict__ ea, const float* __restrict__ W,
    const float* __restrict__ b, const int* __restrict__ inv,
    __half* __restrict__ eah)
{
    __shared__ __half lds_t[4][16 * HID];            // 2KB per wave
    const int lane = threadIdx.x & 63;
    const int waveid = threadIdx.x >> 6;
    const int wave = (blockIdx.x * 256 + threadIdx.x) >> 6;
    const int nwaves = gridDim.x * 4;
    const int m = lane & 15, q = lane >> 4;
    const int NT = N_EDGES / 16;                     // 50000

    half8 bf[4];
#pragma unroll
    for (int blk = 0; blk < 4; ++blk) {
#pragma unroll
        for (int i = 0; i < 8; ++i) {
            const int k = q * 8 + i;
            bf[blk][i] = (k < EDGE_DIM)
                ? (_Float16)W[k * HID + blk * 16 + m] : (_Float16)0.f;
        }
    }
    float bv[4];
#pragma unroll
    for (int blk = 0; blk < 4; ++blk) bv[blk] = b[blk * 16 + m];

    const int ed = lane >> 3, ch = lane & 7;         // store mapping

    for (int tile = wave; tile < NT; tile += nwaves) {
        const int e0 = tile * 16;
        half8 af;
#pragma unroll
        for (int i = 0; i < 8; ++i) af[i] = (_Float16)0.f;
        if (q < 2) {
            const float4* ap =
                (const float4*)(ea + (size_t)(e0 + m) * EDGE_DIM + q * 8);
            const float4 lo = ap[0];
            const float4 hi = ap[1];
            af[0] = (_Float16)lo.x; af[1] = (_Float16)lo.y;
            af[2] = (_Float16)lo.z; af[3] = (_Float16)lo.w;
            af[4] = (_Float16)hi.x; af[5] = (_Float16)hi.y;
            af[6] = (_Float16)hi.z; af[7] = (_Float16)hi.w;
        }
        floatx4 c[4];
#pragma unroll
        for (int blk = 0; blk < 4; ++blk) {
            floatx4 cin = {bv[blk], bv[blk], bv[blk], bv[blk]};
            c[blk] = __builtin_amdgcn_mfma_f32_16x16x32_f16(
                af, bf[blk], cin, 0, 0, 0);
        }
#pragma unroll
        for (int blk = 0; blk < 4; ++blk)
#pragma unroll
            for (int r = 0; r < 4; ++r)
                lds_t[waveid][(q * 4 + r) * HID + blk * 16 + m] =
                    __float2half(c[blk][r]);
        const int pos0 = inv[e0 + ed];
        const int pos1 = inv[e0 + 8 + ed];
        const float4 v0 =
            *(const float4*)&lds_t[waveid][ed * HID + ch * 8];
        const float4 v1 =
            *(const float4*)&lds_t[waveid][(8 + ed) * HID + ch * 8];
        ((float4*)(eah + (size_t)pos0 * HID))[ch] = v0;
        ((float4*)(eah + (size_t)pos1 * HID))[ch] = v1;
    }
}

// ---------------------------------------------------------------------------
// Edge-major segmented softmax-aggregate (packed sd = {src,dst}).
// Depth-2 prefetch: group g+1's 8 z-gathers + 8 eah lines issued before
// computing group g. Boundary ballot -> SALU bit tests. f16 add/relu, exp2.
// ---------------------------------------------------------------------------
__global__ __launch_bounds__(256, 4) void edge_agg_kernel(
    const __half* __restrict__ zh, const __half* __restrict__ eah,
    const int2* __restrict__ sd,
    const float* __restrict__ conv_t, int layer,
    float* __restrict__ p, float* __restrict__ s)
{
    const int lane = threadIdx.x & 63;
    const int wave = (blockIdx.x * 256 + threadIdx.x) >> 6;
    const int nwaves = gridDim.x * 4;
    const float t2 = conv_t[layer] * 1.4426950408889634f;  // log2(e)*t
    const int NT = N_EDGES / 64;                     // 12500

    const _Float16* zf = (const _Float16*)zh;
    const _Float16* ef = (const _Float16*)eah;

    for (int tile = wave; tile < NT; tile += nwaves) {
        const int e0 = tile * 64;
        const int2 sdv = sd[e0 + lane];              // one coalesced 8B load
        const int sv = sdv.x;
        const int dv = sdv.y;
        const int pv = __shfl_up(dv, 1, 64);
        const unsigned long long bmask = __ballot(dv != pv) & ~1ull;
        const _Float16* erow = ef + (size_t)e0 * HID + lane;

        _Float16 za[8], ez[8], zb[8], eb[8];
#pragma unroll
        for (int k = 0; k < 8; ++k) {                // prologue: group 0
            const int a = __builtin_amdgcn_readlane(sv, k);
            za[k] = (zf + (size_t)a * HID)[lane];
            ez[k] = erow[(size_t)k * HID];
        }

        float S = 0.f, P = 0.f;
        int cur = __builtin_amdgcn_readlane(dv, 0);
#pragma unroll
        for (int g = 0; g < 8; ++g) {
            if (g < 7) {                             // prefetch group g+1
#pragma unroll
                for (int k = 0; k < 8; ++k) {
                    const int a = __builtin_amdgcn_readlane(sv, (g + 1) * 8 + k);
                    zb[k] = (zf + (size_t)a * HID)[lane];
                    eb[k] = erow[(size_t)((g + 1) * 8 + k) * HID];
                }
            }
#pragma unroll
            for (int k = 0; k < 8; ++k) {
                const int j = g * 8 + k;
                if (bmask & (1ull << j)) {           // SALU test, uniform
                    unsafeAtomicAdd(&s[(size_t)cur * HID + lane], S);
                    unsafeAtomicAdd(&p[(size_t)cur * HID + lane], P);
                    S = 0.f; P = 0.f;
                    cur = __builtin_amdgcn_readlane(dv, j);
                }
                _Float16 mh = za[k] + ez[k];
                mh = mh > (_Float16)0.f ? mh : (_Float16)0.f;
                const float m = (float)mh + 1e-7f;
                const float xx = __builtin_amdgcn_exp2f(m * t2);
                S += xx;
                P = fmaf(m, xx, P);
            }
            if (g < 7) {
#pragma unroll
                for (int k = 0; k < 8; ++k) { za[k] = zb[k]; ez[k] = eb[k]; }
            }
        }
        unsafeAtomicAdd(&s[(size_t)cur * HID + lane], S);
        unsafeAtomicAdd(&p[(size_t)cur * HID + lane], P);
    }
}

// ---------------------------------------------------------------------------
// mm1: hin = p/(s+eps) + zh ; u = hin@W1 + b1 ; vh = fp16(relu(LN128(u)*g1+be1))
// Also re-zeroes p,s for the next layer's aggregation.
// ---------------------------------------------------------------------------
__global__ __launch_bounds__(256, 2) void node_mm1_kernel(
    float* __restrict__ p, float* __restrict__ s,
    const __half* __restrict__ zh,
    const float* __restrict__ W1, const float* __restrict__ b1,
    const float* __restrict__ g1, const float* __restrict__ be1,
    __half* __restrict__ vh)
{
    __shared__ float hs[2][HID];
    __shared__ float red[2][2][2];
    const int j = threadIdx.x & 127;
    const int local_n = threadIdx.x >> 7;
    const int wavehalf = (threadIdx.x >> 6) & 1;
    float w[HID];
#pragma unroll
    for (int k = 0; k < HID; ++k) w[k] = W1[k * HID2 + j];
    const float bias = b1[j];
    const float g = g1[j];
    const float be = be1[j];

    for (int base = blockIdx.x * 2; base < N_NODES; base += gridDim.x * 2) {
        __syncthreads();
        if (threadIdx.x < 128) {
            int nn = threadIdx.x >> 6, c = threadIdx.x & 63;
            int idx = (base + nn) * HID + c;
            hs[nn][c] = p[idx] / (s[idx] + 1e-16f) + __half2float(zh[idx]);
            p[idx] = 0.f;                            // re-zero for next layer
            s[idx] = 0.f;
        }
        __syncthreads();
        const int n = base + local_n;
        float u = bias;
#pragma unroll
        for (int k4 = 0; k4 < HID / 4; ++k4) {
            float4 hv = ((const float4*)hs[local_n])[k4];
            u = fmaf(hv.x, w[k4 * 4 + 0], u);
            u = fmaf(hv.y, w[k4 * 4 + 1], u);
            u = fmaf(hv.z, w[k4 * 4 + 2], u);
            u = fmaf(hv.w, w[k4 * 4 + 3], u);
        }
        float ps_ = u;
#pragma unroll
        for (int o = 1; o < 64; o <<= 1) ps_ += __shfl_xor(ps_, o, 64);
        if ((threadIdx.x & 63) == 0) red[local_n][0][wavehalf] = ps_;
        __syncthreads();
        const float mu = (red[local_n][0][0] + red[local_n][0][1]) * (1.f / 128.f);
        const float d = u - mu;
        float q = d * d;
#pragma unroll
        for (int o = 1; o < 64; o <<= 1) q += __shfl_xor(q, o, 64);
        if ((threadIdx.x & 63) == 0) red[local_n][1][wavehalf] = q;
        __syncthreads();
        const float var = (red[local_n][1][0] + red[local_n][1][1]) * (1.f / 128.f);
        const float y = d * rsqrtf(var + 1e-5f) * g + be;
        vh[(size_t)n * HID2 + j] = __float2half(y > 0.f ? y : 0.f);
    }
}

// ---------------------------------------------------------------------------
// mm2: out2 = vh@W2 + b2 ; h = (residual? h:0) + out2 ;
//      zh = fp16(relu(LN64(h)*gz+bz))
// ---------------------------------------------------------------------------
__global__ __launch_bounds__(256, 2) void node_mm2_kernel(
    const __half* __restrict__ vh,
    const float* __restrict__ W2, const float* __restrict__ b2,
    const float* __restrict__ lng, const float* __restrict__ lnb,
    float* __restrict__ h, __half* __restrict__ zh, int residual)
{
    __shared__ float vs[4][HID2];
    const int c = threadIdx.x & 63;
    const int local_n = threadIdx.x >> 6;
    float w[HID2];
#pragma unroll
    for (int k = 0; k < HID2; ++k) w[k] = W2[k * HID + c];
    const float bias = b2[c];
    const float g = lng[c];
    const float be = lnb[c];

    for (int base = blockIdx.x * 4; base < N_NODES; base += gridDim.x * 4) {
        __syncthreads();
        {   // stage 4x128 halves -> float LDS (256 threads x half2)
            const __half2* vp = (const __half2*)(vh + (size_t)base * HID2);
            const float2 f = __half22float2(vp[threadIdx.x]);
            const int nn = threadIdx.x >> 6, kk = (threadIdx.x & 63) * 2;
            vs[nn][kk] = f.x;
            vs[nn][kk + 1] = f.y;
        }
        __syncthreads();
        const int n = base + local_n;
        float acc = bias;
#pragma unroll
        for (int k4 = 0; k4 < HID2 / 4; ++k4) {
            float4 vv = ((const float4*)vs[local_n])[k4];
            acc = fmaf(vv.x, w[k4 * 4 + 0], acc);
            acc = fmaf(vv.y, w[k4 * 4 + 1], acc);
            acc = fmaf(vv.z, w[k4 * 4 + 2], acc);
            acc = fmaf(vv.w, w[k4 * 4 + 3], acc);
        }
        const float hn = residual ? (h[n * HID + c] + acc) : acc;
        h[n * HID + c] = hn;
        float ps_ = hn;
#pragma unroll
        for (int o = 1; o < 64; o <<= 1) ps_ += __shfl_xor(ps_, o, 64);
        const float mu = ps_ * (1.f / 64.f);
        const float d = hn - mu;
        float q = d * d;
#pragma unroll
        for (int o = 1; o < 64; o <<= 1) q += __shfl_xor(q, o, 64);
        const float var = q * (1.f / 64.f);
        const float y = d * rsqrtf(var + 1e-5f) * g + be;
        zh[n * HID + c] = __float2half(y > 0.f ? y : 0.f);
    }
}

// ---------------------------------------------------------------------------
// out = zh @ lin_W + lin_b      [N,64]@[64,8]
// ---------------------------------------------------------------------------
__global__ __launch_bounds__(256, 4) void final_kernel(
    const __half* __restrict__ zh, const float* __restrict__ Wl,
    const float* __restrict__ bl, float* __restrict__ out)
{
    __shared__ float wl[HID * OUT_DIM];
    for (int i = threadIdx.x; i < HID * OUT_DIM; i += 256) wl[i] = Wl[i];
    __syncthreads();
    const int total = N_NODES * OUT_DIM;
    for (int idx = blockIdx.x * 256 + threadIdx.x; idx < total;
         idx += gridDim.x * 256) {
        const int n = idx >> 3, o = idx & 7;
        const __half2* zp = (const __half2*)(zh + (size_t)n * HID);
        float acc = bl[o];
#pragma unroll
        for (int k2 = 0; k2 < HID / 2; ++k2) {
            const float2 f = __half22float2(zp[k2]);
            acc = fmaf(f.x, wl[(k2 * 2 + 0) * OUT_DIM + o], acc);
            acc = fmaf(f.y, wl[(k2 * 2 + 1) * OUT_DIM + o], acc);
        }
        out[idx] = acc;
    }
}

// ---------------------------------------------------------------------------
extern "C" void kernel_launch(void* const* d_in, const int* in_sizes, int n_in,
                              void* d_out, int out_size, void* d_ws, size_t ws_size,
                              hipStream_t stream)
{
    const float* x         = (const float*)d_in[0];
    const float* edge_attr = (const float*)d_in[1];
    const float* node_W    = (const float*)d_in[2];
    const float* node_b    = (const float*)d_in[3];
    const float* edge_W    = (const float*)d_in[4];
    const float* edge_b    = (const float*)d_in[5];
    const float* conv_t    = (const float*)d_in[6];
    const float* conv_W1   = (const float*)d_in[7];
    const float* conv_b1   = (const float*)d_in[8];
    const float* conv_g1   = (const float*)d_in[9];
    const float* conv_be1  = (const float*)d_in[10];
    const float* conv_W2   = (const float*)d_in[11];
    const float* conv_b2   = (const float*)d_in[12];
    const float* ln_g      = (const float*)d_in[13];
    const float* ln_b      = (const float*)d_in[14];
    const float* lin_W     = (const float*)d_in[15];
    const float* lin_b     = (const float*)d_in[16];
    const int*   edge_index= (const int*)d_in[17];
    const int*   srcs = edge_index;
    const int*   dsts = edge_index + N_EDGES;
    float* out = (float*)d_out;

    // workspace layout (~160 MB)
    float* h   = (float*)d_ws;                    // N*64
    float* p   = h   + N_NODES * HID;             // N*64
    float* s   = p   + N_NODES * HID;             // N*64 (contiguous w/ p)
    __half* vh  = (__half*)(s + N_NODES * HID);   // N*128 half
    __half* zh  = vh + (size_t)N_NODES * HID2;    // N*64 half
    __half* eah = zh + (size_t)N_NODES * HID;     // E*64 half
    int* deg     = (int*)(eah + (size_t)N_EDGES * HID); // N
    int* cursor  = deg + N_NODES;                 // N
    int* bsum    = cursor + N_NODES;              // 256
    int* bbase   = bsum + 256;                    // 256
    int* inv     = bbase + 256;                   // E
    int2* sd     = (int2*)(inv + N_EDGES);        // E int2 (8B aligned)

    // ---- counting sort of edges by dst (once per call) ----
    hipMemsetAsync(deg, 0, (size_t)N_NODES * sizeof(int), stream);
    hist_kernel<<<N_EDGES / 256, 256, 0, stream>>>(dsts, deg);
    scan1_kernel<<<SCAN_BLOCKS, 256, 0, stream>>>(deg, bsum);
    scan2_kernel<<<1, 256, 0, stream>>>(bsum, bbase);
    scan3_kernel<<<SCAN_BLOCKS, 256, 0, stream>>>(deg, bbase, cursor);
    scatter_kernel<<<N_EDGES / 256, 256, 0, stream>>>(srcs, dsts, cursor, inv, sd);

    node_proj_kernel<<<2048, 256, 0, stream>>>(x, node_W, node_b, h, zh);
    edge_emb_kernel<<<3125, 256, 0, stream>>>(edge_attr, edge_W, edge_b, inv, eah);

    // zero p,s once; node_mm1 re-zeroes them for the next layer
    hipMemsetAsync(p, 0, (size_t)2 * N_NODES * HID * sizeof(float), stream);

    for (int layer = 0; layer < N_LAYERS; ++layer) {
        edge_agg_kernel<<<3125, 256, 0, stream>>>(zh, eah, sd,
                                                  conv_t, layer, p, s);
        node_mm1_kernel<<<2048, 256, 0, stream>>>(
            p, s, zh,
            conv_W1 + (size_t)layer * HID * HID2, conv_b1 + layer * HID2,
            conv_g1 + layer * HID2, conv_be1 + layer * HID2, vh);
        const float* gz = (layer < N_LAYERS - 1) ? (ln_g + (layer + 1) * HID) : ln_g;
        const float* bz = (layer < N_LAYERS - 1) ? (ln_b + (layer + 1) * HID) : ln_b;
        node_mm2_kernel<<<2048, 256, 0, stream>>>(
            vh, conv_W2 + (size_t)layer * HID2 * HID, conv_b2 + layer * HID,
            gz, bz, h, zh, layer > 0 ? 1 : 0);
    }
    final_kernel<<<1024, 256, 0, stream>>>(zh, lin_W, lin_b, out);
}

// Round 10
// 755.024 us; speedup vs baseline: 1.4985x; 1.0534x over previous
//
#include <hip/hip_runtime.h>
#include <hip/hip_fp16.h>

#define N_NODES 50000
#define N_EDGES 800000
#define IN_DIM  128
#define EDGE_DIM 16
#define HID     64
#define HID2    128
#define OUT_DIM 8
#define N_LAYERS 4
#define NBUCK   391        // ceil(50000/128) buckets of 128 dst nodes
#define CCHUNK  4096       // edges per coarse block
#define CBLOCKS 196        // ceil(800000/4096)

typedef _Float16 half8 __attribute__((ext_vector_type(8)));
typedef float floatx4 __attribute__((ext_vector_type(4)));

// ---------------------------------------------------------------------------
// Two-level counting sort by dst.
// Level 1 (coarse, 128-node buckets): LDS histogram -> contiguous per-block
// runs reserved with one global atomic per (block,bucket) -> line-friendly
// 8B-entry writes. Level 2: per-bucket LDS counting sort -> streaming writes.
// Entry packing: word0 = src | dst<<16 (both < 2^16), word1 = edge id.
// ---------------------------------------------------------------------------
__global__ __launch_bounds__(256, 4) void chist_kernel(
    const int* __restrict__ dsts, int* __restrict__ ccnt)
{
    __shared__ int lh[NBUCK];
    for (int i = threadIdx.x; i < NBUCK; i += 256) lh[i] = 0;
    __syncthreads();
    const int base = blockIdx.x * CCHUNK;
#pragma unroll
    for (int i = 0; i < 16; ++i) {
        const int e = base + i * 256 + threadIdx.x;
        if (e < N_EDGES) atomicAdd(&lh[dsts[e] >> 7], 1);
    }
    __syncthreads();
    for (int i = threadIdx.x; i < NBUCK; i += 256)
        if (lh[i]) atomicAdd(&ccnt[i], lh[i]);
}

// single block: exclusive scan of 391 bucket counts -> coff[0..391], ccur copy
__global__ __launch_bounds__(256, 1) void cscan_kernel(
    const int* __restrict__ ccnt, int* __restrict__ coff, int* __restrict__ ccur)
{
    __shared__ int part[512];
    const int t = threadIdx.x;
    part[t]       = (t < NBUCK)       ? ccnt[t]       : 0;
    part[t + 256] = (t + 256 < NBUCK) ? ccnt[t + 256] : 0;
    __syncthreads();
    for (int off = 1; off < 512; off <<= 1) {
        const int v0 = (t >= off) ? part[t - off] : 0;
        const int v1 = (t + 256 >= off) ? part[t + 256 - off] : 0;
        __syncthreads();
        part[t] += v0; part[t + 256] += v1;
        __syncthreads();
    }
    if (t < NBUCK) { const int ex = (t > 0) ? part[t - 1] : 0; coff[t] = ex; ccur[t] = ex; }
    const int i2 = t + 256;
    if (i2 < NBUCK) { coff[i2] = part[i2 - 1]; ccur[i2] = part[i2 - 1]; }
    if (t == 0) coff[NBUCK] = part[NBUCK - 1];
}

__global__ __launch_bounds__(256, 4) void cscatter_kernel(
    const int* __restrict__ srcs, const int* __restrict__ dsts,
    int* __restrict__ ccur, uint2* __restrict__ tmp)
{
    __shared__ int lh[NBUCK], lbase[NBUCK], lrank[NBUCK];
    for (int i = threadIdx.x; i < NBUCK; i += 256) { lh[i] = 0; lrank[i] = 0; }
    __syncthreads();
    const int base = blockIdx.x * CCHUNK;
    int myd[16], mys[16];
#pragma unroll
    for (int i = 0; i < 16; ++i) {
        const int e = base + i * 256 + threadIdx.x;
        if (e < N_EDGES) {
            myd[i] = dsts[e]; mys[i] = srcs[e];
            atomicAdd(&lh[myd[i] >> 7], 1);
        } else myd[i] = -1;
    }
    __syncthreads();
    for (int i = threadIdx.x; i < NBUCK; i += 256) {
        const int c = lh[i];
        lbase[i] = c ? atomicAdd(&ccur[i], c) : 0;
    }
    __syncthreads();
#pragma unroll
    for (int i = 0; i < 16; ++i) {
        if (myd[i] >= 0) {
            const int e = base + i * 256 + threadIdx.x;
            const int b = myd[i] >> 7;
            const int r = atomicAdd(&lrank[b], 1);
            tmp[lbase[b] + r] =
                make_uint2((unsigned)mys[i] | ((unsigned)myd[i] << 16),
                           (unsigned)e);
        }
    }
}

// one block per bucket: LDS counting sort over the 128 local dsts
__global__ __launch_bounds__(256, 1) void fsort_kernel(
    const uint2* __restrict__ tmp, const int* __restrict__ coff,
    unsigned* __restrict__ sd2, int* __restrict__ eid)
{
    __shared__ uint2 ebuf[4096];
    __shared__ int lh[128], lsc[128];
    const int b = blockIdx.x;
    const int lo = coff[b];
    const int cnt = coff[b + 1] - lo;
    if (threadIdx.x < 128) lh[threadIdx.x] = 0;
    __syncthreads();
    for (int i = threadIdx.x; i < cnt; i += 256) {
        const uint2 v = tmp[lo + i];
        ebuf[i] = v;
        atomicAdd(&lh[(int)(v.x >> 16) - b * 128], 1);
    }
    __syncthreads();
    if (threadIdx.x < 128) lsc[threadIdx.x] = lh[threadIdx.x];
    __syncthreads();
    for (int off = 1; off < 128; off <<= 1) {
        int v = 0;
        if (threadIdx.x < 128 && threadIdx.x >= off) v = lsc[threadIdx.x - off];
        __syncthreads();
        if (threadIdx.x < 128) lsc[threadIdx.x] += v;
        __syncthreads();
    }
    if (threadIdx.x < 128) lh[threadIdx.x] = lsc[threadIdx.x] - lh[threadIdx.x];
    __syncthreads();
    for (int i = threadIdx.x; i < cnt; i += 256) {
        const uint2 v = ebuf[i];
        const int d = (int)(v.x >> 16) - b * 128;
        const int pos = atomicAdd(&lh[d], 1);
        sd2[lo + pos] = v.x;
        eid[lo + pos] = (int)v.y;
    }
}

// ---------------------------------------------------------------------------
// h0 = x @ node_W + node_b      [N,128]@[128,64]; also fp16 copy for gathers
// ---------------------------------------------------------------------------
__global__ __launch_bounds__(256, 2) void node_proj_kernel(
    const float* __restrict__ x, const float* __restrict__ W,
    const float* __restrict__ b, float* __restrict__ h, __half* __restrict__ zh)
{
    __shared__ float xs[4][IN_DIM];
    const int c = threadIdx.x & 63;
    const int local_n = threadIdx.x >> 6;
    float w[IN_DIM];
#pragma unroll
    for (int k = 0; k < IN_DIM; ++k) w[k] = W[k * HID + c];
    const float bias = b[c];

    for (int base = blockIdx.x * 4; base < N_NODES; base += gridDim.x * 4) {
        __syncthreads();
#pragma unroll
        for (int i = 0; i < 2; ++i) {
            int idx = threadIdx.x + i * 256;
            int nn = idx >> 7, kk = idx & 127;
            xs[nn][kk] = x[(base + nn) * IN_DIM + kk];
        }
        __syncthreads();
        const int n = base + local_n;
        float acc = bias;
#pragma unroll
        for (int k4 = 0; k4 < IN_DIM / 4; ++k4) {
            float4 xv = ((const float4*)xs[local_n])[k4];
            acc = fmaf(xv.x, w[k4 * 4 + 0], acc);
            acc = fmaf(xv.y, w[k4 * 4 + 1], acc);
            acc = fmaf(xv.z, w[k4 * 4 + 2], acc);
            acc = fmaf(xv.w, w[k4 * 4 + 3], acc);
        }
        h[n * HID + c] = acc;
        zh[n * HID + c] = __float2half(acc);
    }
}

// ---------------------------------------------------------------------------
// edge embedding via MFMA (16 edges/wave, K padded 16->32), LDS transpose.
// Reads ea[eid[pos]] (random 64B full-line gathers), stores eah STREAMING.
// ---------------------------------------------------------------------------
__global__ __launch_bounds__(256, 4) void edge_emb_kernel(
    const float* __restrict__ ea, const float* __restrict__ W,
    const float* __restrict__ b, const int* __restrict__ eid,
    __half* __restrict__ eah)
{
    __shared__ __half lds_t[4][16 * HID];            // 2KB per wave
    const int lane = threadIdx.x & 63;
    const int waveid = threadIdx.x >> 6;
    const int wave = (blockIdx.x * 256 + threadIdx.x) >> 6;
    const int nwaves = gridDim.x * 4;
    const int m = lane & 15, q = lane >> 4;
    const int NT = N_EDGES / 16;                     // 50000

    half8 bf[4];
#pragma unroll
    for (int blk = 0; blk < 4; ++blk) {
#pragma unroll
        for (int i = 0; i < 8; ++i) {
            const int k = q * 8 + i;
            bf[blk][i] = (k < EDGE_DIM)
                ? (_Float16)W[k * HID + blk * 16 + m] : (_Float16)0.f;
        }
    }
    float bv[4];
#pragma unroll
    for (int blk = 0; blk < 4; ++blk) bv[blk] = b[blk * 16 + m];

    const int ed = lane >> 3, ch = lane & 7;         // store mapping

    for (int tile = wave; tile < NT; tile += nwaves) {
        const int e0 = tile * 16;
        const int eidx = eid[e0 + m];                // gather source row id
        half8 af;
#pragma unroll
        for (int i = 0; i < 8; ++i) af[i] = (_Float16)0.f;
        if (q < 2) {
            const float4* ap =
                (const float4*)(ea + (size_t)eidx * EDGE_DIM + q * 8);
            const float4 lo = ap[0];
            const float4 hi = ap[1];
            af[0] = (_Float16)lo.x; af[1] = (_Float16)lo.y;
            af[2] = (_Float16)lo.z; af[3] = (_Float16)lo.w;
            af[4] = (_Float16)hi.x; af[5] = (_Float16)hi.y;
            af[6] = (_Float16)hi.z; af[7] = (_Float16)hi.w;
        }
        floatx4 c[4];
#pragma unroll
        for (int blk = 0; blk < 4; ++blk) {
            floatx4 cin = {bv[blk], bv[blk], bv[blk], bv[blk]};
            c[blk] = __builtin_amdgcn_mfma_f32_16x16x32_f16(
                af, bf[blk], cin, 0, 0, 0);
        }
#pragma unroll
        for (int blk = 0; blk < 4; ++blk)
#pragma unroll
            for (int r = 0; r < 4; ++r)
                lds_t[waveid][(q * 4 + r) * HID + blk * 16 + m] =
                    __float2half(c[blk][r]);
        // streaming contiguous stores: 2x 16B per lane
        const float4 v0 =
            *(const float4*)&lds_t[waveid][ed * HID + ch * 8];
        const float4 v1 =
            *(const float4*)&lds_t[waveid][(8 + ed) * HID + ch * 8];
        ((float4*)(eah + (size_t)(e0 + ed) * HID))[ch] = v0;
        ((float4*)(eah + (size_t)(e0 + 8 + ed) * HID))[ch] = v1;
    }
}

// ---------------------------------------------------------------------------
// Edge-major segmented softmax-aggregate (sd2 = src | dst<<16, 4B/edge).
// Depth-2 prefetch; boundary ballot -> SALU bit tests; f16 add/relu; exp2.
// ---------------------------------------------------------------------------
__global__ __launch_bounds__(256, 4) void edge_agg_kernel(
    const __half* __restrict__ zh, const __half* __restrict__ eah,
    const unsigned* __restrict__ sd2,
    const float* __restrict__ conv_t, int layer,
    float* __restrict__ p, float* __restrict__ s)
{
    const int lane = threadIdx.x & 63;
    const int wave = (blockIdx.x * 256 + threadIdx.x) >> 6;
    const int nwaves = gridDim.x * 4;
    const float t2 = conv_t[layer] * 1.4426950408889634f;  // log2(e)*t
    const int NT = N_EDGES / 64;                     // 12500

    const _Float16* zf = (const _Float16*)zh;
    const _Float16* ef = (const _Float16*)eah;

    for (int tile = wave; tile < NT; tile += nwaves) {
        const int e0 = tile * 64;
        const unsigned sdv = sd2[e0 + lane];         // one coalesced 4B load
        const int sv = (int)(sdv & 0xffffu);
        const int dv = (int)(sdv >> 16);
        const int pv = __shfl_up(dv, 1, 64);
        const unsigned long long bmask = __ballot(dv != pv) & ~1ull;
        const _Float16* erow = ef + (size_t)e0 * HID + lane;

        _Float16 za[8], ez[8], zb[8], eb[8];
#pragma unroll
        for (int k = 0; k < 8; ++k) {                // prologue: group 0
            const int a = __builtin_amdgcn_readlane(sv, k);
            za[k] = (zf + (size_t)a * HID)[lane];
            ez[k] = erow[(size_t)k * HID];
        }

        float S = 0.f, P = 0.f;
        int cur = __builtin_amdgcn_readlane(dv, 0);
#pragma unroll
        for (int g = 0; g < 8; ++g) {
            if (g < 7) {                             // prefetch group g+1
#pragma unroll
                for (int k = 0; k < 8; ++k) {
                    const int a = __builtin_amdgcn_readlane(sv, (g + 1) * 8 + k);
                    zb[k] = (zf + (size_t)a * HID)[lane];
                    eb[k] = erow[(size_t)((g + 1) * 8 + k) * HID];
                }
            }
#pragma unroll
            for (int k = 0; k < 8; ++k) {
                const int j = g * 8 + k;
                if (bmask & (1ull << j)) {           // SALU test, uniform
                    unsafeAtomicAdd(&s[(size_t)cur * HID + lane], S);
                    unsafeAtomicAdd(&p[(size_t)cur * HID + lane], P);
                    S = 0.f; P = 0.f;
                    cur = __builtin_amdgcn_readlane(dv, j);
                }
                _Float16 mh = za[k] + ez[k];
                mh = mh > (_Float16)0.f ? mh : (_Float16)0.f;
                const float m = (float)mh + 1e-7f;
                const float xx = __builtin_amdgcn_exp2f(m * t2);
                S += xx;
                P = fmaf(m, xx, P);
            }
            if (g < 7) {
#pragma unroll
                for (int k = 0; k < 8; ++k) { za[k] = zb[k]; ez[k] = eb[k]; }
            }
        }
        unsafeAtomicAdd(&s[(size_t)cur * HID + lane], S);
        unsafeAtomicAdd(&p[(size_t)cur * HID + lane], P);
    }
}

// ---------------------------------------------------------------------------
// mm1: hin = p/(s+eps) + zh ; u = hin@W1 + b1 ; vh = fp16(relu(LN128(u)*g1+be1))
// Also re-zeroes p,s for the next layer's aggregation.
// ---------------------------------------------------------------------------
__global__ __launch_bounds__(256, 2) void node_mm1_kernel(
    float* __restrict__ p, float* __restrict__ s,
    const __half* __restrict__ zh,
    const float* __restrict__ W1, const float* __restrict__ b1,
    const float* __restrict__ g1, const float* __restrict__ be1,
    __half* __restrict__ vh)
{
    __shared__ float hs[2][HID];
    __shared__ float red[2][2][2];
    const int j = threadIdx.x & 127;
    const int local_n = threadIdx.x >> 7;
    const int wavehalf = (threadIdx.x >> 6) & 1;
    float w[HID];
#pragma unroll
    for (int k = 0; k < HID; ++k) w[k] = W1[k * HID2 + j];
    const float bias = b1[j];
    const float g = g1[j];
    const float be = be1[j];

    for (int base = blockIdx.x * 2; base < N_NODES; base += gridDim.x * 2) {
        __syncthreads();
        if (threadIdx.x < 128) {
            int nn = threadIdx.x >> 6, c = threadIdx.x & 63;
            int idx = (base + nn) * HID + c;
            hs[nn][c] = p[idx] / (s[idx] + 1e-16f) + __half2float(zh[idx]);
            p[idx] = 0.f;                            // re-zero for next layer
            s[idx] = 0.f;
        }
        __syncthreads();
        const int n = base + local_n;
        float u = bias;
#pragma unroll
        for (int k4 = 0; k4 < HID / 4; ++k4) {
            float4 hv = ((const float4*)hs[local_n])[k4];
            u = fmaf(hv.x, w[k4 * 4 + 0], u);
            u = fmaf(hv.y, w[k4 * 4 + 1], u);
            u = fmaf(hv.z, w[k4 * 4 + 2], u);
            u = fmaf(hv.w, w[k4 * 4 + 3], u);
        }
        float ps_ = u;
#pragma unroll
        for (int o = 1; o < 64; o <<= 1) ps_ += __shfl_xor(ps_, o, 64);
        if ((threadIdx.x & 63) == 0) red[local_n][0][wavehalf] = ps_;
        __syncthreads();
        const float mu = (red[local_n][0][0] + red[local_n][0][1]) * (1.f / 128.f);
        const float d = u - mu;
        float q = d * d;
#pragma unroll
        for (int o = 1; o < 64; o <<= 1) q += __shfl_xor(q, o, 64);
        if ((threadIdx.x & 63) == 0) red[local_n][1][wavehalf] = q;
        __syncthreads();
        const float var = (red[local_n][1][0] + red[local_n][1][1]) * (1.f / 128.f);
        const float y = d * rsqrtf(var + 1e-5f) * g + be;
        vh[(size_t)n * HID2 + j] = __float2half(y > 0.f ? y : 0.f);
    }
}

// ---------------------------------------------------------------------------
// mm2: out2 = vh@W2 + b2 ; h = (residual? h:0) + out2 ;
//      zh = fp16(relu(LN64(h)*gz+bz))
// ---------------------------------------------------------------------------
__global__ __launch_bounds__(256, 2) void node_mm2_kernel(
    const __half* __restrict__ vh,
    const float* __restrict__ W2, const float* __restrict__ b2,
    const float* __restrict__ lng, const float* __restrict__ lnb,
    float* __restrict__ h, __half* __restrict__ zh, int residual)
{
    __shared__ float vs[4][HID2];
    const int c = threadIdx.x & 63;
    const int local_n = threadIdx.x >> 6;
    float w[HID2];
#pragma unroll
    for (int k = 0; k < HID2; ++k) w[k] = W2[k * HID + c];
    const float bias = b2[c];
    const float g = lng[c];
    const float be = lnb[c];

    for (int base = blockIdx.x * 4; base < N_NODES; base += gridDim.x * 4) {
        __syncthreads();
        {   // stage 4x128 halves -> float LDS (256 threads x half2)
            const __half2* vp = (const __half2*)(vh + (size_t)base * HID2);
            const float2 f = __half22float2(vp[threadIdx.x]);
            const int nn = threadIdx.x >> 6, kk = (threadIdx.x & 63) * 2;
            vs[nn][kk] = f.x;
            vs[nn][kk + 1] = f.y;
        }
        __syncthreads();
        const int n = base + local_n;
        float acc = bias;
#pragma unroll
        for (int k4 = 0; k4 < HID2 / 4; ++k4) {
            float4 vv = ((const float4*)vs[local_n])[k4];
            acc = fmaf(vv.x, w[k4 * 4 + 0], acc);
            acc = fmaf(vv.y, w[k4 * 4 + 1], acc);
            acc = fmaf(vv.z, w[k4 * 4 + 2], acc);
            acc = fmaf(vv.w, w[k4 * 4 + 3], acc);
        }
        const float hn = residual ? (h[n * HID + c] + acc) : acc;
        h[n * HID + c] = hn;
        float ps_ = hn;
#pragma unroll
        for (int o = 1; o < 64; o <<= 1) ps_ += __shfl_xor(ps_, o, 64);
        const float mu = ps_ * (1.f / 64.f);
        const float d = hn - mu;
        float q = d * d;
#pragma unroll
        for (int o = 1; o < 64; o <<= 1) q += __shfl_xor(q, o, 64);
        const float var = q * (1.f / 64.f);
        const float y = d * rsqrtf(var + 1e-5f) * g + be;
        zh[n * HID + c] = __float2half(y > 0.f ? y : 0.f);
    }
}

// ---------------------------------------------------------------------------
// out = zh @ lin_W + lin_b      [N,64]@[64,8]
// ---------------------------------------------------------------------------
__global__ __launch_bounds__(256, 4) void final_kernel(
    const __half* __restrict__ zh, const float* __restrict__ Wl,
    const float* __restrict__ bl, float* __restrict__ out)
{
    __shared__ float wl[HID * OUT_DIM];
    for (int i = threadIdx.x; i < HID * OUT_DIM; i += 256) wl[i] = Wl[i];
    __syncthreads();
    const int total = N_NODES * OUT_DIM;
    for (int idx = blockIdx.x * 256 + threadIdx.x; idx < total;
         idx += gridDim.x * 256) {
        const int n = idx >> 3, o = idx & 7;
        const __half2* zp = (const __half2*)(zh + (size_t)n * HID);
        float acc = bl[o];
#pragma unroll
        for (int k2 = 0; k2 < HID / 2; ++k2) {
            const float2 f = __half22float2(zp[k2]);
            acc = fmaf(f.x, wl[(k2 * 2 + 0) * OUT_DIM + o], acc);
            acc = fmaf(f.y, wl[(k2 * 2 + 1) * OUT_DIM + o], acc);
        }
        out[idx] = acc;
    }
}

// ---------------------------------------------------------------------------
extern "C" void kernel_launch(void* const* d_in, const int* in_sizes, int n_in,
                              void* d_out, int out_size, void* d_ws, size_t ws_size,
                              hipStream_t stream)
{
    const float* x         = (const float*)d_in[0];
    const float* edge_attr = (const float*)d_in[1];
    const float* node_W    = (const float*)d_in[2];
    const float* node_b    = (const float*)d_in[3];
    const float* edge_W    = (const float*)d_in[4];
    const float* edge_b    = (const float*)d_in[5];
    const float* conv_t    = (const float*)d_in[6];
    const float* conv_W1   = (const float*)d_in[7];
    const float* conv_b1   = (const float*)d_in[8];
    const float* conv_g1   = (const float*)d_in[9];
    const float* conv_be1  = (const float*)d_in[10];
    const float* conv_W2   = (const float*)d_in[11];
    const float* conv_b2   = (const float*)d_in[12];
    const float* ln_g      = (const float*)d_in[13];
    const float* ln_b      = (const float*)d_in[14];
    const float* lin_W     = (const float*)d_in[15];
    const float* lin_b     = (const float*)d_in[16];
    const int*   edge_index= (const int*)d_in[17];
    const int*   srcs = edge_index;
    const int*   dsts = edge_index + N_EDGES;
    float* out = (float*)d_out;

    // workspace layout (~166 MB)
    float* h   = (float*)d_ws;                    // N*64
    float* p   = h   + N_NODES * HID;             // N*64
    float* s   = p   + N_NODES * HID;             // N*64 (contiguous w/ p)
    __half* vh  = (__half*)(s + N_NODES * HID);   // N*128 half
    __half* zh  = vh + (size_t)N_NODES * HID2;    // N*64 half
    __half* eah = zh + (size_t)N_NODES * HID;     // E*64 half
    uint2* tmp  = (uint2*)(eah + (size_t)N_EDGES * HID); // E x 8B
    unsigned* sd2 = (unsigned*)(tmp + N_EDGES);   // E x 4B
    int* eid    = (int*)(sd2 + N_EDGES);          // E x 4B
    int* ccnt   = eid + N_EDGES;                  // NBUCK
    int* coff   = ccnt + NBUCK;                   // NBUCK+1
    int* ccur   = coff + NBUCK + 1;               // NBUCK

    // ---- two-level counting sort of edges by dst ----
    hipMemsetAsync(ccnt, 0, (size_t)NBUCK * sizeof(int), stream);
    chist_kernel<<<CBLOCKS, 256, 0, stream>>>(dsts, ccnt);
    cscan_kernel<<<1, 256, 0, stream>>>(ccnt, coff, ccur);
    cscatter_kernel<<<CBLOCKS, 256, 0, stream>>>(srcs, dsts, ccur, tmp);
    fsort_kernel<<<NBUCK, 256, 0, stream>>>(tmp, coff, sd2, eid);

    node_proj_kernel<<<2048, 256, 0, stream>>>(x, node_W, node_b, h, zh);
    edge_emb_kernel<<<3125, 256, 0, stream>>>(edge_attr, edge_W, edge_b, eid, eah);

    // zero p,s once; node_mm1 re-zeroes them for the next layer
    hipMemsetAsync(p, 0, (size_t)2 * N_NODES * HID * sizeof(float), stream);

    for (int layer = 0; layer < N_LAYERS; ++layer) {
        edge_agg_kernel<<<3125, 256, 0, stream>>>(zh, eah, sd2,
                                                  conv_t, layer, p, s);
        node_mm1_kernel<<<2048, 256, 0, stream>>>(
            p, s, zh,
            conv_W1 + (size_t)layer * HID * HID2, conv_b1 + layer * HID2,
            conv_g1 + layer * HID2, conv_be1 + layer * HID2, vh);
        const float* gz = (layer < N_LAYERS - 1) ? (ln_g + (layer + 1) * HID) : ln_g;
        const float* bz = (layer < N_LAYERS - 1) ? (ln_b + (layer + 1) * HID) : ln_b;
        node_mm2_kernel<<<2048, 256, 0, stream>>>(
            vh, conv_W2 + (size_t)layer * HID2 * HID, conv_b2 + layer * HID,
            gz, bz, h, zh, layer > 0 ? 1 : 0);
    }
    final_kernel<<<1024, 256, 0, stream>>>(zh, lin_W, lin_b, out);
}